// Round 7
// baseline (309.105 us; speedup 1.0000x reference)
//
#include <hip/hip_runtime.h>
#include <cstdint>
#include <cstddef>

#define B_    8
#define N1_   1024
#define N2_   4096
#define C1_   256
#define C2_   128
#define CS_   64
#define CT_   448
#define H_    256
#define ROWS_ (B_ * N2_)   // 32768

typedef __attribute__((ext_vector_type(8))) short bf16x8;
typedef __attribute__((ext_vector_type(4))) float f32x4;
typedef unsigned short ushort_t;
typedef unsigned int   uint_t;

__device__ __forceinline__ ushort_t f2bf(float f) {
    uint_t u = __float_as_uint(f);
    u = (u + 0x7fffu + ((u >> 16) & 1u)) >> 16;   // RNE
    return (ushort_t)u;
}
__device__ __forceinline__ float bf2f(ushort_t h) {
    return __uint_as_float(((uint_t)h) << 16);
}

// ---------------------------------------------------------------- KNN (K=3)
// R5 parallel structure (2 queries/thread, prefetch, 2-stage merge) with the
// PROVEN R4 distance arithmetic: contract-off, (s2+ss)-2*dot, sqrt-domain,
// strict < (index-ordered scan) — bit-identical selection to rounds 1-4.
__global__ __launch_bounds__(256) void knn_kernel(
    const float* __restrict__ p1, const float* __restrict__ p2,
    int* __restrict__ ind, float* __restrict__ wout)
{
#pragma clang fp contract(off)
    __shared__ float4 cand[N1_ + 8];       // (x, y, z, |p|^2)
    __shared__ float  pdd[16][32][3];
    __shared__ int    pdi[16][32][3];
    __shared__ float  pdd2[4][32][3];
    __shared__ int    pdi2[4][32][3];
    const int t = threadIdx.x;
    const int b  = blockIdx.x >> 7;              // 128 blocks per batch
    const int qb = (blockIdx.x & 127) * 32;      // 32 queries per block
    const float* pb1 = p1 + (size_t)b * 3 * N1_;
    for (int i = t; i < N1_; i += 256) {
        float X = pb1[i], Y = pb1[N1_ + i], Z = pb1[2 * N1_ + i];
        cand[i] = make_float4(X, Y, Z, (X * X + Y * Y) + Z * Z);
    }
    const int qp = t & 15, split = t >> 4;
    const int na = qb + 2 * qp, nb = na + 1;
    const float* pb2 = p2 + (size_t)b * 3 * N2_;
    const float ax = pb2[na], ay = pb2[N2_ + na], az = pb2[2 * N2_ + na];
    const float bx = pb2[nb], by = pb2[N2_ + nb], bz = pb2[2 * N2_ + nb];
    const float s2a = (ax * ax + ay * ay) + az * az;
    const float s2b = (bx * bx + by * by) + bz * bz;
    __syncthreads();
    float a0 = 3e38f, a1 = 3e38f, a2 = 3e38f;  int ai0 = 0, ai1 = 0, ai2 = 0;
    float b0 = 3e38f, b1 = 3e38f, b2 = 3e38f;  int bi0 = 0, bi1 = 0, bi2 = 0;
    const int ibeg = split * 64;
    float4 c = cand[ibeg];
    for (int i = ibeg; i < ibeg + 64; ++i) {
        float4 cn = cand[i + 1];              // prefetch (last one unused)
        float dota = (ax * c.x + ay * c.y) + az * c.z;
        float dda  = (s2a + c.w) - 2.0f * dota;
        float da   = sqrtf(fmaxf(dda, 0.0f));
        float dotb = (bx * c.x + by * c.y) + bz * c.z;
        float ddb  = (s2b + c.w) - 2.0f * dotb;
        float db   = sqrtf(fmaxf(ddb, 0.0f));
        if (da < a0)      { a2 = a1; ai2 = ai1; a1 = a0; ai1 = ai0; a0 = da; ai0 = i; }
        else if (da < a1) { a2 = a1; ai2 = ai1; a1 = da; ai1 = i; }
        else if (da < a2) { a2 = da; ai2 = i; }
        if (db < b0)      { b2 = b1; bi2 = bi1; b1 = b0; bi1 = bi0; b0 = db; bi0 = i; }
        else if (db < b1) { b2 = b1; bi2 = bi1; b1 = db; bi1 = i; }
        else if (db < b2) { b2 = db; bi2 = i; }
        c = cn;
    }
    const int qa = 2 * qp, qbq = 2 * qp + 1;
    pdd[split][qa][0] = a0;  pdd[split][qa][1] = a1;  pdd[split][qa][2] = a2;
    pdi[split][qa][0] = ai0; pdi[split][qa][1] = ai1; pdi[split][qa][2] = ai2;
    pdd[split][qbq][0] = b0;  pdd[split][qbq][1] = b1;  pdd[split][qbq][2] = b2;
    pdi[split][qbq][0] = bi0; pdi[split][qbq][1] = bi1; pdi[split][qbq][2] = bi2;
    __syncthreads();
    if (t < 128) {                               // stage A: 4 splits -> 1
        const int q = t & 31, g = t >> 5;
        float e0 = 3e38f, e1 = 3e38f, e2 = 3e38f;
        int   j0 = 0, j1 = 0, j2 = 0;
#pragma unroll
        for (int s = 0; s < 4; ++s) {
            const int sp = g * 4 + s;
#pragma unroll
            for (int r = 0; r < 3; ++r) {
                float d = pdd[sp][q][r];
                int   i = pdi[sp][q][r];
                if (d < e0)      { e2 = e1; j2 = j1; e1 = e0; j1 = j0; e0 = d; j0 = i; }
                else if (d < e1) { e2 = e1; j2 = j1; e1 = d;  j1 = i; }
                else if (d < e2) { e2 = d;  j2 = i; }
            }
        }
        pdd2[g][q][0] = e0; pdd2[g][q][1] = e1; pdd2[g][q][2] = e2;
        pdi2[g][q][0] = j0; pdi2[g][q][1] = j1; pdi2[g][q][2] = j2;
    }
    __syncthreads();
    if (t < 32) {                                // stage B: 4 groups -> final
        float e0 = 3e38f, e1 = 3e38f, e2 = 3e38f;
        int   j0 = 0, j1 = 0, j2 = 0;
#pragma unroll
        for (int g = 0; g < 4; ++g) {
#pragma unroll
            for (int r = 0; r < 3; ++r) {
                float d = pdd2[g][t][r];
                int   i = pdi2[g][t][r];
                if (d < e0)      { e2 = e1; j2 = j1; e1 = e0; j1 = j0; e0 = d; j0 = i; }
                else if (d < e1) { e2 = e1; j2 = j1; e1 = d;  j1 = i; }
                else if (d < e2) { e2 = d;  j2 = i; }
            }
        }
        float inv0 = 1.0f / (e0 + 1e-10f);
        float inv1 = 1.0f / (e1 + 1e-10f);
        float inv2 = 1.0f / (e2 + 1e-10f);
        float s = (inv0 + inv1) + inv2;
        const size_t row = (size_t)b * N2_ + qb + t;
        wout[row * 3 + 0] = inv0 / s;
        wout[row * 3 + 1] = inv1 / s;
        wout[row * 3 + 2] = inv2 / s;
        ind[row * 3 + 0] = j0;
        ind[row * 3 + 1] = j1;
        ind[row * 3 + 2] = j2;
    }
}

// ------------------------------- merged prep: transpose_f1 | transpose_f2s | convert_w
__global__ __launch_bounds__(256) void prep_kernel(
    const float* __restrict__ f1, const float* __restrict__ f2,
    const float* __restrict__ fs, const float* __restrict__ W1,
    const float* __restrict__ W2, ushort_t* __restrict__ f1t,
    ushort_t* __restrict__ x, ushort_t* __restrict__ W1b, ushort_t* __restrict__ W2b)
{
    __shared__ float tile[64][65];
    const int t = threadIdx.x;
    const int bid0 = blockIdx.x;
    if (bid0 < 512) {                        // transpose f1 -> f1t [B,N1,C1] bf16
        const int bid = bid0;
        const int b  = bid >> 6;
        const int ct = (bid >> 4) & 3;
        const int nt = bid & 15;
        const int c0 = ct * 64, n0 = nt * 64;
        const float* src = f1 + ((size_t)b * C1_ + c0) * N1_ + n0;
#pragma unroll
        for (int j = 0; j < 16; ++j) {
            int lin = j * 256 + t;
            int ci = lin >> 6, nj = lin & 63;
            tile[ci][nj] = src[(size_t)ci * N1_ + nj];
        }
        __syncthreads();
        ushort_t* dst = f1t + ((size_t)b * N1_ + n0) * C1_ + c0;
#pragma unroll
        for (int j = 0; j < 8; ++j) {
            int lin = j * 256 + t;
            int ni = lin >> 5, cjp = (lin & 31) * 2;
            uint_t u = (uint_t)f2bf(tile[cjp][ni]) | ((uint_t)f2bf(tile[cjp + 1][ni]) << 16);
            *(uint_t*)&dst[(size_t)ni * C1_ + cjp] = u;
        }
    } else if (bid0 < 2048) {                // transpose f2/skip -> x tail cols
        const int bid = bid0 - 512;
        const int b   = bid / 192;
        const int rem = bid - b * 192;
        const int ct  = rem >> 6;
        const int nt  = rem & 63;
        const float* src;
        int coff;
        if (ct < 2) { src = f2 + ((size_t)b * C2_ + ct * 64) * N2_; coff = C1_ + ct * 64; }
        else        { src = fs + (size_t)b * CS_ * N2_;             coff = C1_ + C2_; }
        const int n0 = nt * 64;
#pragma unroll
        for (int j = 0; j < 16; ++j) {
            int lin = j * 256 + t;
            int ci = lin >> 6, nj = lin & 63;
            tile[ci][nj] = src[(size_t)ci * N2_ + n0 + nj];
        }
        __syncthreads();
#pragma unroll
        for (int j = 0; j < 8; ++j) {
            int lin = j * 256 + t;
            int ni = lin >> 5, cjp = (lin & 31) * 2;
            uint_t u = (uint_t)f2bf(tile[cjp][ni]) | ((uint_t)f2bf(tile[cjp + 1][ni]) << 16);
            *(uint_t*)&x[((size_t)b * N2_ + n0 + ni) * CT_ + coff + cjp] = u;
        }
    } else {                                 // convert W1/W2 -> bf16
        const int i = (bid0 - 2048) * 256 + t;
        if (i < H_ * CT_) W1b[i] = f2bf(W1[i]);
        if (i < H_ * H_)  W2b[i] = f2bf(W2[i]);
    }
}

// ------------------------------- gather+interp -> x_bf16[:, 0:256]
__global__ __launch_bounds__(256) void gather_x(
    const ushort_t* __restrict__ f1t, const int* __restrict__ ind,
    const float* __restrict__ w, ushort_t* __restrict__ x)
{
    const int t = threadIdx.x;
    const int row = blockIdx.x * 8 + (t >> 5);
    const int b = row >> 12;
    const int cg = (t & 31) * 8;
    const int*   ip = ind + (size_t)row * 3;
    const float* wp = w   + (size_t)row * 3;
    const int i0 = ip[0], i1 = ip[1], i2 = ip[2];
    const float w0 = wp[0], w1 = wp[1], w2 = wp[2];
    const ushort_t* base = f1t + (size_t)b * N1_ * C1_;
    uint4 va = *(const uint4*)(base + (size_t)i0 * C1_ + cg);
    uint4 vb = *(const uint4*)(base + (size_t)i1 * C1_ + cg);
    uint4 vc = *(const uint4*)(base + (size_t)i2 * C1_ + cg);
    const uint_t* pa = (const uint_t*)&va;
    const uint_t* pb = (const uint_t*)&vb;
    const uint_t* pc = (const uint_t*)&vc;
    uint_t out[4];
#pragma unroll
    for (int e = 0; e < 4; ++e) {
        float lo = w0 * bf2f((ushort_t)(pa[e] & 0xffff))
                 + w1 * bf2f((ushort_t)(pb[e] & 0xffff))
                 + w2 * bf2f((ushort_t)(pc[e] & 0xffff));
        float hi = w0 * bf2f((ushort_t)(pa[e] >> 16))
                 + w1 * bf2f((ushort_t)(pb[e] >> 16))
                 + w2 * bf2f((ushort_t)(pc[e] >> 16));
        out[e] = (uint_t)f2bf(lo) | ((uint_t)f2bf(hi) << 16);
    }
    *(uint4*)&x[(size_t)row * CT_ + cg] = *(uint4*)out;
}

// ------------------------------- bf16 GEMM (shared by both layers):
// C[m,n] = bf16( A[m,:K]·Bw[n,:K] + bias[n] ), fused per-channel sum/sumsq.
// 128x64 tile, BK=64, stride-72 LDS (bank-uniform), grid (256,4).
__global__ __launch_bounds__(256, 4) void gemm_bf16(
    const ushort_t* __restrict__ A, const ushort_t* __restrict__ Bw,
    const float* __restrict__ bias, ushort_t* __restrict__ C,
    float* __restrict__ ssum, float* __restrict__ ssq, int K)
{
    __shared__ __align__(16) ushort_t As[128 * 72];
    __shared__ __align__(16) ushort_t Bs[64 * 72];
    const int t = threadIdx.x;
    const int m0 = blockIdx.x * 128;
    const int n0 = blockIdx.y * 64;
    const int lane = t & 63;
    const int wv = t >> 6;
    const int wrow = wv & 1, wcol = wv >> 1;     // 2x2 waves: 64 rows x 32 cols
    const int lm = lane & 15, lq = lane >> 4;
    const int arow = t & 127, akg = (t >> 7) * 4;   // A: 4 chunks/thread
    const int brow = t & 63,  bkg = (t >> 6) * 2;   // B: 2 chunks/thread
    f32x4 acc[4][2];
#pragma unroll
    for (int i = 0; i < 4; ++i)
#pragma unroll
        for (int j = 0; j < 2; ++j)
            acc[i][j] = (f32x4){0.f, 0.f, 0.f, 0.f};

    for (int k0 = 0; k0 < K; k0 += 64) {
        uint4 av[4], bv[2];
#pragma unroll
        for (int qq = 0; qq < 4; ++qq)
            av[qq] = *(const uint4*)(A + (size_t)(m0 + arow) * K + k0 + (akg + qq) * 8);
#pragma unroll
        for (int qq = 0; qq < 2; ++qq)
            bv[qq] = *(const uint4*)(Bw + (size_t)(n0 + brow) * K + k0 + (bkg + qq) * 8);
        __syncthreads();
#pragma unroll
        for (int qq = 0; qq < 4; ++qq)
            *(uint4*)&As[arow * 72 + (akg + qq) * 8] = av[qq];
#pragma unroll
        for (int qq = 0; qq < 2; ++qq)
            *(uint4*)&Bs[brow * 72 + (bkg + qq) * 8] = bv[qq];
        __syncthreads();
#pragma unroll
        for (int h = 0; h < 2; ++h) {
            bf16x8 af[4], bfr[2];
#pragma unroll
            for (int i = 0; i < 4; ++i)
                af[i] = *(const bf16x8*)&As[(wrow * 64 + i * 16 + lm) * 72 + h * 32 + lq * 8];
#pragma unroll
            for (int j = 0; j < 2; ++j)
                bfr[j] = *(const bf16x8*)&Bs[(wcol * 32 + j * 16 + lm) * 72 + h * 32 + lq * 8];
#pragma unroll
            for (int i = 0; i < 4; ++i)
#pragma unroll
                for (int j = 0; j < 2; ++j)
                    acc[i][j] = __builtin_amdgcn_mfma_f32_16x16x32_bf16(af[i], bfr[j], acc[i][j], 0, 0, 0);
        }
        __syncthreads();
    }
#pragma unroll
    for (int j = 0; j < 2; ++j) {
        const int gn = n0 + wcol * 32 + j * 16 + lm;
        const float bb = bias[gn];
        float ps = 0.0f, pq = 0.0f;
#pragma unroll
        for (int i = 0; i < 4; ++i) {
            const int gm = m0 + wrow * 64 + i * 16 + lq * 4;
            f32x4 v = acc[i][j];
#pragma unroll
            for (int r = 0; r < 4; ++r) {
                float val = v[r] + bb;
                C[(size_t)(gm + r) * H_ + gn] = f2bf(val);
                ps += val;
                pq += val * val;
            }
        }
        ps += __shfl_xor(ps, 16); pq += __shfl_xor(pq, 16);
        ps += __shfl_xor(ps, 32); pq += __shfl_xor(pq, 32);
        if (lane < 16) {
            atomicAdd(&ssum[gn], ps);
            atomicAdd(&ssq[gn], pq);
        }
    }
}

// ------------------------------- BN1 + ReLU: y1b (bf16, raw) -> y1n (bf16, normalized)
__global__ __launch_bounds__(256) void bn_relu_mid(
    const ushort_t* __restrict__ y, const float* __restrict__ ssum,
    const float* __restrict__ ssq, const float* __restrict__ g,
    const float* __restrict__ beta, ushort_t* __restrict__ yn)
{
    __shared__ float sc[H_], sh[H_];
    const int t = threadIdx.x;
    {
        const float invN = 1.0f / (float)ROWS_;
        float mu  = ssum[t] * invN;
        float var = ssq[t] * invN - mu * mu;
        float s   = rsqrtf(var + 1e-3f) * g[t];
        sc[t] = s;
        sh[t] = beta[t] - mu * s;
    }
    __syncthreads();
    const int c0 = (t & 31) * 8;
    float s[8], h[8];
#pragma unroll
    for (int e = 0; e < 8; ++e) { s[e] = sc[c0 + e]; h[e] = sh[c0 + e]; }
    const uint4* yin = (const uint4*)y;
    uint4* yout = (uint4*)yn;
    const size_t base = (size_t)blockIdx.x * 4096 + t;
#pragma unroll
    for (int j = 0; j < 16; ++j) {
        uint4 u = yin[base + j * 256];
        uint_t* uw = (uint_t*)&u;
        uint_t o[4];
#pragma unroll
        for (int e = 0; e < 4; ++e) {
            float lo = __uint_as_float(uw[e] << 16);
            float hi = __uint_as_float(uw[e] & 0xffff0000u);
            float rlo = fmaxf(fmaf(lo, s[2 * e],     h[2 * e]),     0.0f);
            float rhi = fmaxf(fmaf(hi, s[2 * e + 1], h[2 * e + 1]), 0.0f);
            o[e] = (uint_t)f2bf(rlo) | ((uint_t)f2bf(rhi) << 16);
        }
        yout[base + j * 256] = *(uint4*)o;
    }
}

// ------------------------------- BN2 + ReLU + transpose, bf16 y2 -> out[B,256,N2] fp32
__global__ __launch_bounds__(256) void bn_out_kernel(
    const ushort_t* __restrict__ y, const float* __restrict__ ssum, const float* __restrict__ ssq,
    const float* __restrict__ g, const float* __restrict__ beta, float* __restrict__ out)
{
    __shared__ float tile[64][65];
    __shared__ float sc[64], sh[64];
    const float invN = 1.0f / (float)ROWS_;
    const int bid = blockIdx.x;
    const int b  = bid >> 8;
    const int nt = (bid >> 2) & 63;
    const int ot = bid & 3;
    const int t = threadIdx.x;
    if (t < 64) {
        int c = ot * 64 + t;
        float mu  = ssum[c] * invN;
        float var = ssq[c] * invN - mu * mu;
        float s   = rsqrtf(var + 1e-3f) * g[c];
        sc[t] = s;
        sh[t] = beta[c] - mu * s;
    }
    __syncthreads();
    const int n0 = nt * 64, o0 = ot * 64;
    const ushort_t* yb = y + ((size_t)b * N2_ + n0) * H_ + o0;
#pragma unroll
    for (int j = 0; j < 8; ++j) {
        int lin = j * 256 + t;
        int nl = lin >> 5, cu = (lin & 31) * 2;
        uint_t u = *(const uint_t*)&yb[(size_t)nl * H_ + cu];
        tile[nl][cu]     = fmaxf(bf2f((ushort_t)(u & 0xffff)) * sc[cu]     + sh[cu],     0.0f);
        tile[nl][cu + 1] = fmaxf(bf2f((ushort_t)(u >> 16))    * sc[cu + 1] + sh[cu + 1], 0.0f);
    }
    __syncthreads();
    float* ob = out + ((size_t)b * H_ + o0) * N2_ + n0;
#pragma unroll
    for (int j = 0; j < 16; ++j) {
        int lin = j * 256 + t;
        int ol = lin >> 6, nl = lin & 63;
        ob[(size_t)ol * N2_ + nl] = tile[nl][ol];
    }
}

// ----------------------------------------------------------------------------
extern "C" void kernel_launch(void* const* d_in, const int* in_sizes, int n_in,
                              void* d_out, int out_size, void* d_ws, size_t ws_size,
                              hipStream_t stream)
{
    (void)in_sizes; (void)n_in; (void)out_size; (void)ws_size;
    const float* points1   = (const float*)d_in[0];
    const float* points2   = (const float*)d_in[1];
    const float* features1 = (const float*)d_in[2];
    const float* features2 = (const float*)d_in[3];
    const float* skipf     = (const float*)d_in[4];
    const float* W1  = (const float*)d_in[5];
    const float* b1  = (const float*)d_in[6];
    const float* g1  = (const float*)d_in[7];
    const float* be1 = (const float*)d_in[8];
    const float* W2  = (const float*)d_in[9];
    const float* b2  = (const float*)d_in[10];
    const float* g2  = (const float*)d_in[11];
    const float* be2 = (const float*)d_in[12];
    float* out = (float*)d_out;

    char* ws = (char*)d_ws;
    float*    s1  = (float*)(ws + 0);
    float*    q1  = (float*)(ws + 1024);
    float*    s2  = (float*)(ws + 2048);
    float*    q2  = (float*)(ws + 3072);
    int*      ind = (int*)(ws + 4096);                 // 393216 B
    float*    wgt = (float*)(ws + 397312);             // 393216 B
    ushort_t* x   = (ushort_t*)(ws + 790528);          // 29,360,128 B (bf16 32768x448)
    ushort_t* y1b = (ushort_t*)(ws + 30150656);        // 16,777,216 B (bf16 raw y1)
    ushort_t* y1n = (ushort_t*)(ws + 46927872);        // 16,777,216 B (bf16 BN1+ReLU(y1))
    ushort_t* W1b = (ushort_t*)(ws + 63705088);        // 229,376 B
    ushort_t* W2b = (ushort_t*)(ws + 63934464);        // 131,072 B
    ushort_t* f1t = (ushort_t*)(ws + 64065536);        // 4,194,304 B (bf16 8x1024x256)
    ushort_t* y2b = x;                                 // alias: x dead after gemm1

    hipMemsetAsync(ws, 0, 4096, stream);               // zero BN stats

    knn_kernel<<<dim3(1024), dim3(256), 0, stream>>>(points1, points2, ind, wgt);
    prep_kernel<<<dim3(2496), dim3(256), 0, stream>>>(features1, features2, skipf,
                                                      W1, W2, f1t, x, W1b, W2b);
    gather_x<<<dim3(4096), dim3(256), 0, stream>>>(f1t, ind, wgt, x);

    gemm_bf16<<<dim3(ROWS_ / 128, 4), dim3(256), 0, stream>>>(x, W1b, b1, y1b, s1, q1, CT_);
    bn_relu_mid<<<dim3(256), dim3(256), 0, stream>>>(y1b, s1, q1, g1, be1, y1n);
    gemm_bf16<<<dim3(ROWS_ / 128, 4), dim3(256), 0, stream>>>(y1n, W2b, b2, y2b, s2, q2, H_);
    bn_out_kernel<<<dim3(2048), dim3(256), 0, stream>>>(y2b, s2, q2, g2, be2, out);
}

// Round 8
// 236.083 us; speedup vs baseline: 1.3093x; 1.3093x over previous
//
#include <hip/hip_runtime.h>
#include <cstdint>
#include <cstddef>

#define B_    8
#define N1_   1024
#define N2_   4096
#define C1_   256
#define C2_   128
#define CS_   64
#define CT_   448
#define H_    256
#define ROWS_ (B_ * N2_)   // 32768

typedef __attribute__((ext_vector_type(8))) short bf16x8;
typedef __attribute__((ext_vector_type(4))) float f32x4;
typedef unsigned short ushort_t;
typedef unsigned int   uint_t;

__device__ __forceinline__ ushort_t f2bf(float f) {
    uint_t u = __float_as_uint(f);
    u = (u + 0x7fffu + ((u >> 16) & 1u)) >> 16;   // RNE
    return (ushort_t)u;
}
__device__ __forceinline__ float bf2f(ushort_t h) {
    return __uint_as_float(((uint_t)h) << 16);
}

// ---------------------------------------------------------------- KNN (K=3)
// Parallel structure: 2 queries/thread, prefetch, 2-stage merge. Distance
// arithmetic is the PROVEN R4 form: contract-off, (s2+ss)-2*dot, sqrt-domain,
// strict < on index-ordered scan (top_k tie-break preserved). DO NOT change
// the expression order — R5's d^2-domain variant flipped a neighbor (absmax 1.1).
__global__ __launch_bounds__(256) void knn_kernel(
    const float* __restrict__ p1, const float* __restrict__ p2,
    int* __restrict__ ind, float* __restrict__ wout)
{
#pragma clang fp contract(off)
    __shared__ float4 cand[N1_ + 8];       // (x, y, z, |p|^2)
    __shared__ float  pdd[16][32][3];
    __shared__ int    pdi[16][32][3];
    __shared__ float  pdd2[4][32][3];
    __shared__ int    pdi2[4][32][3];
    const int t = threadIdx.x;
    const int b  = blockIdx.x >> 7;              // 128 blocks per batch
    const int qb = (blockIdx.x & 127) * 32;      // 32 queries per block
    const float* pb1 = p1 + (size_t)b * 3 * N1_;
    for (int i = t; i < N1_; i += 256) {
        float X = pb1[i], Y = pb1[N1_ + i], Z = pb1[2 * N1_ + i];
        cand[i] = make_float4(X, Y, Z, (X * X + Y * Y) + Z * Z);
    }
    const int qp = t & 15, split = t >> 4;
    const int na = qb + 2 * qp, nb = na + 1;
    const float* pb2 = p2 + (size_t)b * 3 * N2_;
    const float ax = pb2[na], ay = pb2[N2_ + na], az = pb2[2 * N2_ + na];
    const float bx = pb2[nb], by = pb2[N2_ + nb], bz = pb2[2 * N2_ + nb];
    const float s2a = (ax * ax + ay * ay) + az * az;
    const float s2b = (bx * bx + by * by) + bz * bz;
    __syncthreads();
    float a0 = 3e38f, a1 = 3e38f, a2 = 3e38f;  int ai0 = 0, ai1 = 0, ai2 = 0;
    float b0 = 3e38f, b1 = 3e38f, b2 = 3e38f;  int bi0 = 0, bi1 = 0, bi2 = 0;
    const int ibeg = split * 64;
    float4 c = cand[ibeg];
    for (int i = ibeg; i < ibeg + 64; ++i) {
        float4 cn = cand[i + 1];              // prefetch (last one unused)
        float dota = (ax * c.x + ay * c.y) + az * c.z;
        float dda  = (s2a + c.w) - 2.0f * dota;
        float da   = sqrtf(fmaxf(dda, 0.0f));
        float dotb = (bx * c.x + by * c.y) + bz * c.z;
        float ddb  = (s2b + c.w) - 2.0f * dotb;
        float db   = sqrtf(fmaxf(ddb, 0.0f));
        if (da < a0)      { a2 = a1; ai2 = ai1; a1 = a0; ai1 = ai0; a0 = da; ai0 = i; }
        else if (da < a1) { a2 = a1; ai2 = ai1; a1 = da; ai1 = i; }
        else if (da < a2) { a2 = da; ai2 = i; }
        if (db < b0)      { b2 = b1; bi2 = bi1; b1 = b0; bi1 = bi0; b0 = db; bi0 = i; }
        else if (db < b1) { b2 = b1; bi2 = bi1; b1 = db; bi1 = i; }
        else if (db < b2) { b2 = db; bi2 = i; }
        c = cn;
    }
    const int qa = 2 * qp, qbq = 2 * qp + 1;
    pdd[split][qa][0] = a0;  pdd[split][qa][1] = a1;  pdd[split][qa][2] = a2;
    pdi[split][qa][0] = ai0; pdi[split][qa][1] = ai1; pdi[split][qa][2] = ai2;
    pdd[split][qbq][0] = b0;  pdd[split][qbq][1] = b1;  pdd[split][qbq][2] = b2;
    pdi[split][qbq][0] = bi0; pdi[split][qbq][1] = bi1; pdi[split][qbq][2] = bi2;
    __syncthreads();
    if (t < 128) {                               // stage A: 4 splits -> 1
        const int q = t & 31, g = t >> 5;
        float e0 = 3e38f, e1 = 3e38f, e2 = 3e38f;
        int   j0 = 0, j1 = 0, j2 = 0;
#pragma unroll
        for (int s = 0; s < 4; ++s) {
            const int sp = g * 4 + s;
#pragma unroll
            for (int r = 0; r < 3; ++r) {
                float d = pdd[sp][q][r];
                int   i = pdi[sp][q][r];
                if (d < e0)      { e2 = e1; j2 = j1; e1 = e0; j1 = j0; e0 = d; j0 = i; }
                else if (d < e1) { e2 = e1; j2 = j1; e1 = d;  j1 = i; }
                else if (d < e2) { e2 = d;  j2 = i; }
            }
        }
        pdd2[g][q][0] = e0; pdd2[g][q][1] = e1; pdd2[g][q][2] = e2;
        pdi2[g][q][0] = j0; pdi2[g][q][1] = j1; pdi2[g][q][2] = j2;
    }
    __syncthreads();
    if (t < 32) {                                // stage B: 4 groups -> final
        float e0 = 3e38f, e1 = 3e38f, e2 = 3e38f;
        int   j0 = 0, j1 = 0, j2 = 0;
#pragma unroll
        for (int g = 0; g < 4; ++g) {
#pragma unroll
            for (int r = 0; r < 3; ++r) {
                float d = pdd2[g][t][r];
                int   i = pdi2[g][t][r];
                if (d < e0)      { e2 = e1; j2 = j1; e1 = e0; j1 = j0; e0 = d; j0 = i; }
                else if (d < e1) { e2 = e1; j2 = j1; e1 = d;  j1 = i; }
                else if (d < e2) { e2 = d;  j2 = i; }
            }
        }
        float inv0 = 1.0f / (e0 + 1e-10f);
        float inv1 = 1.0f / (e1 + 1e-10f);
        float inv2 = 1.0f / (e2 + 1e-10f);
        float s = (inv0 + inv1) + inv2;
        const size_t row = (size_t)b * N2_ + qb + t;
        wout[row * 3 + 0] = inv0 / s;
        wout[row * 3 + 1] = inv1 / s;
        wout[row * 3 + 2] = inv2 / s;
        ind[row * 3 + 0] = j0;
        ind[row * 3 + 1] = j1;
        ind[row * 3 + 2] = j2;
    }
}

// ------------------------------- merged prep: transpose_f1 | transpose_f2s | convert_w
__global__ __launch_bounds__(256) void prep_kernel(
    const float* __restrict__ f1, const float* __restrict__ f2,
    const float* __restrict__ fs, const float* __restrict__ W1,
    const float* __restrict__ W2, ushort_t* __restrict__ f1t,
    ushort_t* __restrict__ x, ushort_t* __restrict__ W1b, ushort_t* __restrict__ W2b)
{
    __shared__ float tile[64][65];
    const int t = threadIdx.x;
    const int bid0 = blockIdx.x;
    if (bid0 < 512) {                        // transpose f1 -> f1t [B,N1,C1] bf16
        const int bid = bid0;
        const int b  = bid >> 6;
        const int ct = (bid >> 4) & 3;
        const int nt = bid & 15;
        const int c0 = ct * 64, n0 = nt * 64;
        const float* src = f1 + ((size_t)b * C1_ + c0) * N1_ + n0;
#pragma unroll
        for (int j = 0; j < 16; ++j) {
            int lin = j * 256 + t;
            int ci = lin >> 6, nj = lin & 63;
            tile[ci][nj] = src[(size_t)ci * N1_ + nj];
        }
        __syncthreads();
        ushort_t* dst = f1t + ((size_t)b * N1_ + n0) * C1_ + c0;
#pragma unroll
        for (int j = 0; j < 8; ++j) {
            int lin = j * 256 + t;
            int ni = lin >> 5, cjp = (lin & 31) * 2;
            uint_t u = (uint_t)f2bf(tile[cjp][ni]) | ((uint_t)f2bf(tile[cjp + 1][ni]) << 16);
            *(uint_t*)&dst[(size_t)ni * C1_ + cjp] = u;
        }
    } else if (bid0 < 2048) {                // transpose f2/skip -> x tail cols
        const int bid = bid0 - 512;
        const int b   = bid / 192;
        const int rem = bid - b * 192;
        const int ct  = rem >> 6;
        const int nt  = rem & 63;
        const float* src;
        int coff;
        if (ct < 2) { src = f2 + ((size_t)b * C2_ + ct * 64) * N2_; coff = C1_ + ct * 64; }
        else        { src = fs + (size_t)b * CS_ * N2_;             coff = C1_ + C2_; }
        const int n0 = nt * 64;
#pragma unroll
        for (int j = 0; j < 16; ++j) {
            int lin = j * 256 + t;
            int ci = lin >> 6, nj = lin & 63;
            tile[ci][nj] = src[(size_t)ci * N2_ + n0 + nj];
        }
        __syncthreads();
#pragma unroll
        for (int j = 0; j < 8; ++j) {
            int lin = j * 256 + t;
            int ni = lin >> 5, cjp = (lin & 31) * 2;
            uint_t u = (uint_t)f2bf(tile[cjp][ni]) | ((uint_t)f2bf(tile[cjp + 1][ni]) << 16);
            *(uint_t*)&x[((size_t)b * N2_ + n0 + ni) * CT_ + coff + cjp] = u;
        }
    } else {                                 // convert W1/W2 -> bf16
        const int i = (bid0 - 2048) * 256 + t;
        if (i < H_ * CT_) W1b[i] = f2bf(W1[i]);
        if (i < H_ * H_)  W2b[i] = f2bf(W2[i]);
    }
}

// ------------------------------- gather+interp -> x_bf16[:, 0:256]
__global__ __launch_bounds__(256) void gather_x(
    const ushort_t* __restrict__ f1t, const int* __restrict__ ind,
    const float* __restrict__ w, ushort_t* __restrict__ x)
{
    const int t = threadIdx.x;
    const int row = blockIdx.x * 8 + (t >> 5);
    const int b = row >> 12;
    const int cg = (t & 31) * 8;
    const int*   ip = ind + (size_t)row * 3;
    const float* wp = w   + (size_t)row * 3;
    const int i0 = ip[0], i1 = ip[1], i2 = ip[2];
    const float w0 = wp[0], w1 = wp[1], w2 = wp[2];
    const ushort_t* base = f1t + (size_t)b * N1_ * C1_;
    uint4 va = *(const uint4*)(base + (size_t)i0 * C1_ + cg);
    uint4 vb = *(const uint4*)(base + (size_t)i1 * C1_ + cg);
    uint4 vc = *(const uint4*)(base + (size_t)i2 * C1_ + cg);
    const uint_t* pa = (const uint_t*)&va;
    const uint_t* pb = (const uint_t*)&vb;
    const uint_t* pc = (const uint_t*)&vc;
    uint_t out[4];
#pragma unroll
    for (int e = 0; e < 4; ++e) {
        float lo = w0 * bf2f((ushort_t)(pa[e] & 0xffff))
                 + w1 * bf2f((ushort_t)(pb[e] & 0xffff))
                 + w2 * bf2f((ushort_t)(pc[e] & 0xffff));
        float hi = w0 * bf2f((ushort_t)(pa[e] >> 16))
                 + w1 * bf2f((ushort_t)(pb[e] >> 16))
                 + w2 * bf2f((ushort_t)(pc[e] >> 16));
        out[e] = (uint_t)f2bf(lo) | ((uint_t)f2bf(hi) << 16);
    }
    *(uint4*)&x[(size_t)row * CT_ + cg] = *(uint4*)out;
}

// ------------------------------- bf16 GEMM (both layers):
// C[m,n] = bf16( A[m,:K]·Bw[n,:K] + bias[n] ), fused per-channel sum/sumsq.
// R4-proven K-loop (128x64 tile, BK=32, stride-40 LDS, coalesced 64B staging)
// + NEW: C-tile routed through LDS (union with As/Bs) so global stores cover
// full 128B lines (uint4/lane, 8 lanes/row) — kills the 9x write amplification.
__global__ __launch_bounds__(256, 4) void gemm_bf16(
    const ushort_t* __restrict__ A, const ushort_t* __restrict__ Bw,
    const float* __restrict__ bias, ushort_t* __restrict__ C,
    float* __restrict__ ssum, float* __restrict__ ssq, int K)
{
    __shared__ __align__(16) ushort_t smem[128 * 72];   // 18.4 KB union
    ushort_t* As = smem;                 // 128 x 40 (5120 shorts)
    ushort_t* Bs = smem + 5120;          //  64 x 40 (2560 shorts)
    ushort_t* Cs = smem;                 // 128 x 72 epilogue tile (reuse)
    const int t = threadIdx.x;
    const int m0 = blockIdx.x * 128;
    const int n0 = blockIdx.y * 64;
    const int lane = t & 63;
    const int wv = t >> 6;
    const int wrow = wv & 1, wcol = wv >> 1;     // 2x2 waves: 64 rows x 32 cols
    const int lm = lane & 15, lq = lane >> 4;
    const int crow = t >> 2, ckc = (t & 3) * 8;  // staging: 4 lanes cover 64B/row
    f32x4 acc[4][2];
#pragma unroll
    for (int i = 0; i < 4; ++i)
#pragma unroll
        for (int j = 0; j < 2; ++j)
            acc[i][j] = (f32x4){0.f, 0.f, 0.f, 0.f};

    for (int k0 = 0; k0 < K; k0 += 32) {
        uint4 a0 = *(const uint4*)(A  + (size_t)(m0 + crow) * K + k0 + ckc);
        uint4 a1 = *(const uint4*)(A  + (size_t)(m0 + 64 + crow) * K + k0 + ckc);
        uint4 b0 = *(const uint4*)(Bw + (size_t)(n0 + crow) * K + k0 + ckc);
        __syncthreads();
        *(uint4*)&As[crow * 40 + ckc]        = a0;
        *(uint4*)&As[(64 + crow) * 40 + ckc] = a1;
        *(uint4*)&Bs[crow * 40 + ckc]        = b0;
        __syncthreads();
        bf16x8 af[4], bfr[2];
#pragma unroll
        for (int i = 0; i < 4; ++i)
            af[i] = *(const bf16x8*)&As[(wrow * 64 + i * 16 + lm) * 40 + lq * 8];
#pragma unroll
        for (int j = 0; j < 2; ++j)
            bfr[j] = *(const bf16x8*)&Bs[(wcol * 32 + j * 16 + lm) * 40 + lq * 8];
#pragma unroll
        for (int i = 0; i < 4; ++i)
#pragma unroll
            for (int j = 0; j < 2; ++j)
                acc[i][j] = __builtin_amdgcn_mfma_f32_16x16x32_bf16(af[i], bfr[j], acc[i][j], 0, 0, 0);
    }
    __syncthreads();                 // all waves done reading As/Bs -> reuse as Cs
#pragma unroll
    for (int j = 0; j < 2; ++j) {
        const int gn_l = wcol * 32 + j * 16 + lm;
        const int gn   = n0 + gn_l;
        const float bb = bias[gn];
        float ps = 0.0f, pq = 0.0f;
#pragma unroll
        for (int i = 0; i < 4; ++i) {
            const int row_l = wrow * 64 + i * 16 + lq * 4;
            f32x4 v = acc[i][j];
#pragma unroll
            for (int r = 0; r < 4; ++r) {
                float val = v[r] + bb;
                ps += val;
                pq += val * val;
                float vo = __shfl_xor(val, 1);   // partner column (lm^1)
                uint_t packed = (lm & 1)
                    ? ((uint_t)f2bf(vo)  | ((uint_t)f2bf(val) << 16))
                    : ((uint_t)f2bf(val) | ((uint_t)f2bf(vo)  << 16));
                if ((lm & 1) == 0)
                    *(uint_t*)&Cs[(row_l + r) * 72 + (gn_l & ~1)] = packed;
            }
        }
        ps += __shfl_xor(ps, 16); pq += __shfl_xor(pq, 16);
        ps += __shfl_xor(ps, 32); pq += __shfl_xor(pq, 32);
        if (lane < 16) {
            atomicAdd(&ssum[gn], ps);
            atomicAdd(&ssq[gn], pq);
        }
    }
    __syncthreads();
    const int srow = t >> 3;             // 0..31
    const int scol = (t & 7) * 8;        // 8 lanes cover a full 128B row
#pragma unroll
    for (int rep = 0; rep < 4; ++rep) {
        const int row = srow + rep * 32;
        uint4 v = *(const uint4*)&Cs[row * 72 + scol];
        *(uint4*)(C + (size_t)(m0 + row) * H_ + n0 + scol) = v;
    }
}

// ------------------------------- BN1 + ReLU: y1b (bf16, raw) -> y1n (bf16, normalized)
__global__ __launch_bounds__(256) void bn_relu_mid(
    const ushort_t* __restrict__ y, const float* __restrict__ ssum,
    const float* __restrict__ ssq, const float* __restrict__ g,
    const float* __restrict__ beta, ushort_t* __restrict__ yn)
{
    __shared__ float sc[H_], sh[H_];
    const int t = threadIdx.x;
    {
        const float invN = 1.0f / (float)ROWS_;
        float mu  = ssum[t] * invN;
        float var = ssq[t] * invN - mu * mu;
        float s   = rsqrtf(var + 1e-3f) * g[t];
        sc[t] = s;
        sh[t] = beta[t] - mu * s;
    }
    __syncthreads();
    const int c0 = (t & 31) * 8;
    float s[8], h[8];
#pragma unroll
    for (int e = 0; e < 8; ++e) { s[e] = sc[c0 + e]; h[e] = sh[c0 + e]; }
    const uint4* yin = (const uint4*)y;
    uint4* yout = (uint4*)yn;
    const size_t base = (size_t)blockIdx.x * 4096 + t;
#pragma unroll
    for (int j = 0; j < 16; ++j) {
        uint4 u = yin[base + j * 256];
        uint_t* uw = (uint_t*)&u;
        uint_t o[4];
#pragma unroll
        for (int e = 0; e < 4; ++e) {
            float lo = __uint_as_float(uw[e] << 16);
            float hi = __uint_as_float(uw[e] & 0xffff0000u);
            float rlo = fmaxf(fmaf(lo, s[2 * e],     h[2 * e]),     0.0f);
            float rhi = fmaxf(fmaf(hi, s[2 * e + 1], h[2 * e + 1]), 0.0f);
            o[e] = (uint_t)f2bf(rlo) | ((uint_t)f2bf(rhi) << 16);
        }
        yout[base + j * 256] = *(uint4*)o;
    }
}

// ------------------------------- BN2 + ReLU + transpose, bf16 y2 -> out[B,256,N2] fp32
__global__ __launch_bounds__(256) void bn_out_kernel(
    const ushort_t* __restrict__ y, const float* __restrict__ ssum, const float* __restrict__ ssq,
    const float* __restrict__ g, const float* __restrict__ beta, float* __restrict__ out)
{
    __shared__ float tile[64][65];
    __shared__ float sc[64], sh[64];
    const float invN = 1.0f / (float)ROWS_;
    const int bid = blockIdx.x;
    const int b  = bid >> 8;
    const int nt = (bid >> 2) & 63;
    const int ot = bid & 3;
    const int t = threadIdx.x;
    if (t < 64) {
        int c = ot * 64 + t;
        float mu  = ssum[c] * invN;
        float var = ssq[c] * invN - mu * mu;
        float s   = rsqrtf(var + 1e-3f) * g[c];
        sc[t] = s;
        sh[t] = beta[c] - mu * s;
    }
    __syncthreads();
    const int n0 = nt * 64, o0 = ot * 64;
    const ushort_t* yb = y + ((size_t)b * N2_ + n0) * H_ + o0;
#pragma unroll
    for (int j = 0; j < 8; ++j) {
        int lin = j * 256 + t;
        int nl = lin >> 5, cu = (lin & 31) * 2;
        uint_t u = *(const uint_t*)&yb[(size_t)nl * H_ + cu];
        tile[nl][cu]     = fmaxf(bf2f((ushort_t)(u & 0xffff)) * sc[cu]     + sh[cu],     0.0f);
        tile[nl][cu + 1] = fmaxf(bf2f((ushort_t)(u >> 16))    * sc[cu + 1] + sh[cu + 1], 0.0f);
    }
    __syncthreads();
    float* ob = out + ((size_t)b * H_ + o0) * N2_ + n0;
#pragma unroll
    for (int j = 0; j < 16; ++j) {
        int lin = j * 256 + t;
        int ol = lin >> 6, nl = lin & 63;
        ob[(size_t)ol * N2_ + nl] = tile[nl][ol];
    }
}

// ----------------------------------------------------------------------------
extern "C" void kernel_launch(void* const* d_in, const int* in_sizes, int n_in,
                              void* d_out, int out_size, void* d_ws, size_t ws_size,
                              hipStream_t stream)
{
    (void)in_sizes; (void)n_in; (void)out_size; (void)ws_size;
    const float* points1   = (const float*)d_in[0];
    const float* points2   = (const float*)d_in[1];
    const float* features1 = (const float*)d_in[2];
    const float* features2 = (const float*)d_in[3];
    const float* skipf     = (const float*)d_in[4];
    const float* W1  = (const float*)d_in[5];
    const float* b1  = (const float*)d_in[6];
    const float* g1  = (const float*)d_in[7];
    const float* be1 = (const float*)d_in[8];
    const float* W2  = (const float*)d_in[9];
    const float* b2  = (const float*)d_in[10];
    const float* g2  = (const float*)d_in[11];
    const float* be2 = (const float*)d_in[12];
    float* out = (float*)d_out;

    char* ws = (char*)d_ws;
    float*    s1  = (float*)(ws + 0);
    float*    q1  = (float*)(ws + 1024);
    float*    s2  = (float*)(ws + 2048);
    float*    q2  = (float*)(ws + 3072);
    int*      ind = (int*)(ws + 4096);                 // 393216 B
    float*    wgt = (float*)(ws + 397312);             // 393216 B
    ushort_t* x   = (ushort_t*)(ws + 790528);          // 29,360,128 B (bf16 32768x448)
    ushort_t* y1b = (ushort_t*)(ws + 30150656);        // 16,777,216 B (bf16 raw y1)
    ushort_t* y1n = (ushort_t*)(ws + 46927872);        // 16,777,216 B (bf16 BN1+ReLU(y1))
    ushort_t* W1b = (ushort_t*)(ws + 63705088);        // 229,376 B
    ushort_t* W2b = (ushort_t*)(ws + 63934464);        // 131,072 B
    ushort_t* f1t = (ushort_t*)(ws + 64065536);        // 4,194,304 B (bf16 8x1024x256)
    ushort_t* y2b = x;                                 // alias: x dead after gemm1

    hipMemsetAsync(ws, 0, 4096, stream);               // zero BN stats

    knn_kernel<<<dim3(1024), dim3(256), 0, stream>>>(points1, points2, ind, wgt);
    prep_kernel<<<dim3(2496), dim3(256), 0, stream>>>(features1, features2, skipf,
                                                      W1, W2, f1t, x, W1b, W2b);
    gather_x<<<dim3(4096), dim3(256), 0, stream>>>(f1t, ind, wgt, x);

    gemm_bf16<<<dim3(ROWS_ / 128, 4), dim3(256), 0, stream>>>(x, W1b, b1, y1b, s1, q1, CT_);
    bn_relu_mid<<<dim3(256), dim3(256), 0, stream>>>(y1b, s1, q1, g1, be1, y1n);
    gemm_bf16<<<dim3(ROWS_ / 128, 4), dim3(256), 0, stream>>>(y1n, W2b, b2, y2b, s2, q2, H_);
    bn_out_kernel<<<dim3(2048), dim3(256), 0, stream>>>(y2b, s2, q2, g2, be2, out);
}

// Round 9
// 215.096 us; speedup vs baseline: 1.4371x; 1.0976x over previous
//
#include <hip/hip_runtime.h>
#include <cstdint>
#include <cstddef>

#define B_    8
#define N1_   1024
#define N2_   4096
#define C1_   256
#define C2_   128
#define CS_   64
#define CT_   448
#define H_    256
#define ROWS_ (B_ * N2_)   // 32768

typedef __attribute__((ext_vector_type(8))) short bf16x8;
typedef __attribute__((ext_vector_type(4))) float f32x4;
typedef unsigned short ushort_t;
typedef unsigned int   uint_t;

__device__ __forceinline__ ushort_t f2bf(float f) {
    uint_t u = __float_as_uint(f);
    u = (u + 0x7fffu + ((u >> 16) & 1u)) >> 16;   // RNE
    return (ushort_t)u;
}
__device__ __forceinline__ float bf2f(ushort_t h) {
    return __uint_as_float(((uint_t)h) << 16);
}

// ---------------------------------------------------------------- fused KNN + prep
// bid < 512: KNN. Exact-filtered two-pass:
//   phase 1: fast fma d^2, value-only top-3 (fmin/med3) -> threshold+2e-3 margin
//   phase 2: rescan fast, compact survivor indices (ascending) to LDS lists
//   phase 3: bit-exact R4 arithmetic (contract-off, (s2+ss)-2*dot, sqrt-domain,
//            strict <) on survivors only + proven quarter-merge.
//   Margin 2e-3 >> 2e-5 worst-case |fast-exact| => selection identical to full
//   exact scan (incl. sqrt-collapse ties, which lie within ~1e-5 of dd3).
// bid >= 512: prep (transpose f1 / f2+skip / convert W) — code unchanged from R8.
__global__ __launch_bounds__(256) void fused_pre(
    const float* __restrict__ p1, const float* __restrict__ p2,
    int* __restrict__ ind, float* __restrict__ wout,
    const float* __restrict__ f1, const float* __restrict__ f2,
    const float* __restrict__ fs, const float* __restrict__ W1,
    const float* __restrict__ W2, ushort_t* __restrict__ f1t,
    ushort_t* __restrict__ x, ushort_t* __restrict__ W1b, ushort_t* __restrict__ W2b)
{
#pragma clang fp contract(off)
    __shared__ __align__(16) char smem[32000];
    const int t = threadIdx.x;
    const int bid = blockIdx.x;
    if (bid < 512) {
        float4*   cand  = (float4*)(smem);             // 1024 x (x,y,z,|p|^2), 16384 B
        float*    pvals = (float*)(smem + 16384);      // [256][3] fast top-3 vals, 3072 B
        float*    thr   = (float*)(smem + 19456);      // [64], 256 B
        ushort_t* lists = (ushort_t*)(smem + 19712);   // [64][4][12], 6144 B
        float*    pdd   = (float*)(smem + 25856);      // [4][64][3], 3072 B
        int*      pdi   = (int*)(smem + 28928);        // [4][64][3], 3072 B
        const int b  = bid >> 6;                 // 64 blocks per batch
        const int qb = (bid & 63) * 64;          // 64 queries per block
        const float* pb1 = p1 + (size_t)b * 3 * N1_;
        for (int i = t; i < N1_; i += 256) {
            float X = pb1[i], Y = pb1[N1_ + i], Z = pb1[2 * N1_ + i];
            cand[i] = make_float4(X, Y, Z, (X * X + Y * Y) + Z * Z);
        }
        const int q = t & 63, quarter = t >> 6;
        const int n = qb + q;
        const float* pb2 = p2 + (size_t)b * 3 * N2_;
        const float ax = pb2[n], ay = pb2[N2_ + n], az = pb2[2 * N2_ + n];
        const float s2a = (ax * ax + ay * ay) + az * az;
        const float m2x = -2.0f * ax, m2y = -2.0f * ay, m2z = -2.0f * az;
        __syncthreads();
        // ---- phase 1: fast value-only top-3 over this quarter
        const int ibeg = quarter * 256, iend = ibeg + 256;
        {
            float a0 = 3e38f, a1 = 3e38f, a2 = 3e38f;
            for (int i = ibeg; i < iend; ++i) {
                float4 c = cand[i];
                float fd = fmaf(c.x, m2x, fmaf(c.y, m2y, fmaf(c.z, m2z, s2a + c.w)));
                float o0 = a0, o1 = a1;
                a0 = fminf(o0, fd);
                a1 = __builtin_amdgcn_fmed3f(fd, o0, o1);
                a2 = __builtin_amdgcn_fmed3f(fd, o1, a2);
            }
            pvals[t * 3 + 0] = a0; pvals[t * 3 + 1] = a1; pvals[t * 3 + 2] = a2;
        }
        __syncthreads();
        if (t < 64) {
            float m0 = 3e38f, m1 = 3e38f, m2v = 3e38f;
#pragma unroll
            for (int g = 0; g < 4; ++g)
#pragma unroll
                for (int r = 0; r < 3; ++r) {
                    float v = pvals[(g * 64 + t) * 3 + r];
                    float o0 = m0, o1 = m1;
                    m0 = fminf(o0, v);
                    m1 = __builtin_amdgcn_fmed3f(v, o0, o1);
                    m2v = __builtin_amdgcn_fmed3f(v, o1, m2v);
                }
            thr[t] = m2v + 2e-3f;
        }
        __syncthreads();
        // ---- phase 2: compact survivors (ascending index within quarter)
        const float th = thr[q];
        ushort_t* mylist = lists + (q * 4 + quarter) * 12;
        int cnt = 0;
        for (int i = ibeg; i < iend; ++i) {
            float4 c = cand[i];
            float fd = fmaf(c.x, m2x, fmaf(c.y, m2y, fmaf(c.z, m2z, s2a + c.w)));
            if (fd <= th && cnt < 12) { mylist[cnt] = (ushort_t)i; cnt++; }
        }
        // ---- phase 3a: exact top-3 over survivors (R4-proven arithmetic)
        float e0 = 3e38f, e1 = 3e38f, e2 = 3e38f;
        int   j0 = 0, j1 = 0, j2 = 0;
        for (int k = 0; k < cnt; ++k) {
            const int i = mylist[k];
            float4 c = cand[i];
            float dot = (ax * c.x + ay * c.y) + az * c.z;
            float dd  = (s2a + c.w) - 2.0f * dot;
            float d   = sqrtf(fmaxf(dd, 0.0f));
            if (d < e0)      { e2 = e1; j2 = j1; e1 = e0; j1 = j0; e0 = d; j0 = i; }
            else if (d < e1) { e2 = e1; j2 = j1; e1 = d;  j1 = i; }
            else if (d < e2) { e2 = d;  j2 = i; }
        }
        pdd[(quarter * 64 + q) * 3 + 0] = e0; pdi[(quarter * 64 + q) * 3 + 0] = j0;
        pdd[(quarter * 64 + q) * 3 + 1] = e1; pdi[(quarter * 64 + q) * 3 + 1] = j1;
        pdd[(quarter * 64 + q) * 3 + 2] = e2; pdi[(quarter * 64 + q) * 3 + 2] = j2;
        __syncthreads();
        // ---- phase 3b: merge quarters in ascending order (proven semantics)
        if (t < 64) {
            float f0 = 3e38f, f1v = 3e38f, f2v = 3e38f;
            int   k0 = 0, k1 = 0, k2 = 0;
#pragma unroll
            for (int g = 0; g < 4; ++g)
#pragma unroll
                for (int r = 0; r < 3; ++r) {
                    float d = pdd[(g * 64 + t) * 3 + r];
                    int   i = pdi[(g * 64 + t) * 3 + r];
                    if (d < f0)       { f2v = f1v; k2 = k1; f1v = f0; k1 = k0; f0 = d; k0 = i; }
                    else if (d < f1v) { f2v = f1v; k2 = k1; f1v = d;  k1 = i; }
                    else if (d < f2v) { f2v = d;  k2 = i; }
                }
            float inv0 = 1.0f / (f0 + 1e-10f);
            float inv1 = 1.0f / (f1v + 1e-10f);
            float inv2 = 1.0f / (f2v + 1e-10f);
            float s = (inv0 + inv1) + inv2;
            const size_t row = (size_t)b * N2_ + qb + t;
            wout[row * 3 + 0] = inv0 / s;
            wout[row * 3 + 1] = inv1 / s;
            wout[row * 3 + 2] = inv2 / s;
            ind[row * 3 + 0] = k0;
            ind[row * 3 + 1] = k1;
            ind[row * 3 + 2] = k2;
        }
    } else if (bid < 1024) {                 // transpose f1 -> f1t [B,N1,C1] bf16
        float (*tile)[65] = (float (*)[65])smem;
        const int bid2 = bid - 512;
        const int b  = bid2 >> 6;
        const int ct = (bid2 >> 4) & 3;
        const int nt = bid2 & 15;
        const int c0 = ct * 64, n0 = nt * 64;
        const float* src = f1 + ((size_t)b * C1_ + c0) * N1_ + n0;
#pragma unroll
        for (int j = 0; j < 16; ++j) {
            int lin = j * 256 + t;
            int ci = lin >> 6, nj = lin & 63;
            tile[ci][nj] = src[(size_t)ci * N1_ + nj];
        }
        __syncthreads();
        ushort_t* dst = f1t + ((size_t)b * N1_ + n0) * C1_ + c0;
#pragma unroll
        for (int j = 0; j < 8; ++j) {
            int lin = j * 256 + t;
            int ni = lin >> 5, cjp = (lin & 31) * 2;
            uint_t u = (uint_t)f2bf(tile[cjp][ni]) | ((uint_t)f2bf(tile[cjp + 1][ni]) << 16);
            *(uint_t*)&dst[(size_t)ni * C1_ + cjp] = u;
        }
    } else if (bid < 2560) {                 // transpose f2/skip -> x tail cols
        float (*tile)[65] = (float (*)[65])smem;
        const int bid2 = bid - 1024;
        const int b   = bid2 / 192;
        const int rem = bid2 - b * 192;
        const int ct  = rem >> 6;
        const int nt  = rem & 63;
        const float* src;
        int coff;
        if (ct < 2) { src = f2 + ((size_t)b * C2_ + ct * 64) * N2_; coff = C1_ + ct * 64; }
        else        { src = fs + (size_t)b * CS_ * N2_;             coff = C1_ + C2_; }
        const int n0 = nt * 64;
#pragma unroll
        for (int j = 0; j < 16; ++j) {
            int lin = j * 256 + t;
            int ci = lin >> 6, nj = lin & 63;
            tile[ci][nj] = src[(size_t)ci * N2_ + n0 + nj];
        }
        __syncthreads();
#pragma unroll
        for (int j = 0; j < 8; ++j) {
            int lin = j * 256 + t;
            int ni = lin >> 5, cjp = (lin & 31) * 2;
            uint_t u = (uint_t)f2bf(tile[cjp][ni]) | ((uint_t)f2bf(tile[cjp + 1][ni]) << 16);
            *(uint_t*)&x[((size_t)b * N2_ + n0 + ni) * CT_ + coff + cjp] = u;
        }
    } else {                                 // convert W1/W2 -> bf16
        const int i = (bid - 2560) * 256 + t;
        if (i < H_ * CT_) W1b[i] = f2bf(W1[i]);
        if (i < H_ * H_)  W2b[i] = f2bf(W2[i]);
    }
}

// ------------------------------- gather+interp -> x_bf16[:, 0:256]
__global__ __launch_bounds__(256) void gather_x(
    const ushort_t* __restrict__ f1t, const int* __restrict__ ind,
    const float* __restrict__ w, ushort_t* __restrict__ x)
{
    const int t = threadIdx.x;
    const int row = blockIdx.x * 8 + (t >> 5);
    const int b = row >> 12;
    const int cg = (t & 31) * 8;
    const int*   ip = ind + (size_t)row * 3;
    const float* wp = w   + (size_t)row * 3;
    const int i0 = ip[0], i1 = ip[1], i2 = ip[2];
    const float w0 = wp[0], w1 = wp[1], w2 = wp[2];
    const ushort_t* base = f1t + (size_t)b * N1_ * C1_;
    uint4 va = *(const uint4*)(base + (size_t)i0 * C1_ + cg);
    uint4 vb = *(const uint4*)(base + (size_t)i1 * C1_ + cg);
    uint4 vc = *(const uint4*)(base + (size_t)i2 * C1_ + cg);
    const uint_t* pa = (const uint_t*)&va;
    const uint_t* pb = (const uint_t*)&vb;
    const uint_t* pc = (const uint_t*)&vc;
    uint_t out[4];
#pragma unroll
    for (int e = 0; e < 4; ++e) {
        float lo = w0 * bf2f((ushort_t)(pa[e] & 0xffff))
                 + w1 * bf2f((ushort_t)(pb[e] & 0xffff))
                 + w2 * bf2f((ushort_t)(pc[e] & 0xffff));
        float hi = w0 * bf2f((ushort_t)(pa[e] >> 16))
                 + w1 * bf2f((ushort_t)(pb[e] >> 16))
                 + w2 * bf2f((ushort_t)(pc[e] >> 16));
        out[e] = (uint_t)f2bf(lo) | ((uint_t)f2bf(hi) << 16);
    }
    *(uint4*)&x[(size_t)row * CT_ + cg] = *(uint4*)out;
}

// ------------------------------- bf16 GEMM (both layers) — R8-proven.
__global__ __launch_bounds__(256, 4) void gemm_bf16(
    const ushort_t* __restrict__ A, const ushort_t* __restrict__ Bw,
    const float* __restrict__ bias, ushort_t* __restrict__ C,
    float* __restrict__ ssum, float* __restrict__ ssq, int K)
{
    __shared__ __align__(16) ushort_t smem[128 * 72];   // 18.4 KB union
    ushort_t* As = smem;                 // 128 x 40
    ushort_t* Bs = smem + 5120;          //  64 x 40
    ushort_t* Cs = smem;                 // 128 x 72 epilogue tile (reuse)
    const int t = threadIdx.x;
    const int m0 = blockIdx.x * 128;
    const int n0 = blockIdx.y * 64;
    const int lane = t & 63;
    const int wv = t >> 6;
    const int wrow = wv & 1, wcol = wv >> 1;
    const int lm = lane & 15, lq = lane >> 4;
    const int crow = t >> 2, ckc = (t & 3) * 8;
    f32x4 acc[4][2];
#pragma unroll
    for (int i = 0; i < 4; ++i)
#pragma unroll
        for (int j = 0; j < 2; ++j)
            acc[i][j] = (f32x4){0.f, 0.f, 0.f, 0.f};

    for (int k0 = 0; k0 < K; k0 += 32) {
        uint4 a0 = *(const uint4*)(A  + (size_t)(m0 + crow) * K + k0 + ckc);
        uint4 a1 = *(const uint4*)(A  + (size_t)(m0 + 64 + crow) * K + k0 + ckc);
        uint4 b0 = *(const uint4*)(Bw + (size_t)(n0 + crow) * K + k0 + ckc);
        __syncthreads();
        *(uint4*)&As[crow * 40 + ckc]        = a0;
        *(uint4*)&As[(64 + crow) * 40 + ckc] = a1;
        *(uint4*)&Bs[crow * 40 + ckc]        = b0;
        __syncthreads();
        bf16x8 af[4], bfr[2];
#pragma unroll
        for (int i = 0; i < 4; ++i)
            af[i] = *(const bf16x8*)&As[(wrow * 64 + i * 16 + lm) * 40 + lq * 8];
#pragma unroll
        for (int j = 0; j < 2; ++j)
            bfr[j] = *(const bf16x8*)&Bs[(wcol * 32 + j * 16 + lm) * 40 + lq * 8];
#pragma unroll
        for (int i = 0; i < 4; ++i)
#pragma unroll
            for (int j = 0; j < 2; ++j)
                acc[i][j] = __builtin_amdgcn_mfma_f32_16x16x32_bf16(af[i], bfr[j], acc[i][j], 0, 0, 0);
    }
    __syncthreads();
#pragma unroll
    for (int j = 0; j < 2; ++j) {
        const int gn_l = wcol * 32 + j * 16 + lm;
        const int gn   = n0 + gn_l;
        const float bb = bias[gn];
        float ps = 0.0f, pq = 0.0f;
#pragma unroll
        for (int i = 0; i < 4; ++i) {
            const int row_l = wrow * 64 + i * 16 + lq * 4;
            f32x4 v = acc[i][j];
#pragma unroll
            for (int r = 0; r < 4; ++r) {
                float val = v[r] + bb;
                ps += val;
                pq += val * val;
                float vo = __shfl_xor(val, 1);
                uint_t packed = (lm & 1)
                    ? ((uint_t)f2bf(vo)  | ((uint_t)f2bf(val) << 16))
                    : ((uint_t)f2bf(val) | ((uint_t)f2bf(vo)  << 16));
                if ((lm & 1) == 0)
                    *(uint_t*)&Cs[(row_l + r) * 72 + (gn_l & ~1)] = packed;
            }
        }
        ps += __shfl_xor(ps, 16); pq += __shfl_xor(pq, 16);
        ps += __shfl_xor(ps, 32); pq += __shfl_xor(pq, 32);
        if (lane < 16) {
            atomicAdd(&ssum[gn], ps);
            atomicAdd(&ssq[gn], pq);
        }
    }
    __syncthreads();
    const int srow = t >> 3;
    const int scol = (t & 7) * 8;
#pragma unroll
    for (int rep = 0; rep < 4; ++rep) {
        const int row = srow + rep * 32;
        uint4 v = *(const uint4*)&Cs[row * 72 + scol];
        *(uint4*)(C + (size_t)(m0 + row) * H_ + n0 + scol) = v;
    }
}

// ------------------------------- BN1 + ReLU: y1b (bf16, raw) -> y1n (bf16, normalized)
__global__ __launch_bounds__(256) void bn_relu_mid(
    const ushort_t* __restrict__ y, const float* __restrict__ ssum,
    const float* __restrict__ ssq, const float* __restrict__ g,
    const float* __restrict__ beta, ushort_t* __restrict__ yn)
{
    __shared__ float sc[H_], sh[H_];
    const int t = threadIdx.x;
    {
        const float invN = 1.0f / (float)ROWS_;
        float mu  = ssum[t] * invN;
        float var = ssq[t] * invN - mu * mu;
        float s   = rsqrtf(var + 1e-3f) * g[t];
        sc[t] = s;
        sh[t] = beta[t] - mu * s;
    }
    __syncthreads();
    const int c0 = (t & 31) * 8;
    float s[8], h[8];
#pragma unroll
    for (int e = 0; e < 8; ++e) { s[e] = sc[c0 + e]; h[e] = sh[c0 + e]; }
    const uint4* yin = (const uint4*)y;
    uint4* yout = (uint4*)yn;
    const size_t base = (size_t)blockIdx.x * 4096 + t;
#pragma unroll
    for (int j = 0; j < 16; ++j) {
        uint4 u = yin[base + j * 256];
        uint_t* uw = (uint_t*)&u;
        uint_t o[4];
#pragma unroll
        for (int e = 0; e < 4; ++e) {
            float lo = __uint_as_float(uw[e] << 16);
            float hi = __uint_as_float(uw[e] & 0xffff0000u);
            float rlo = fmaxf(fmaf(lo, s[2 * e],     h[2 * e]),     0.0f);
            float rhi = fmaxf(fmaf(hi, s[2 * e + 1], h[2 * e + 1]), 0.0f);
            o[e] = (uint_t)f2bf(rlo) | ((uint_t)f2bf(rhi) << 16);
        }
        yout[base + j * 256] = *(uint4*)o;
    }
}

// ------------------------------- BN2 + ReLU + transpose, bf16 y2 -> out[B,256,N2] fp32
__global__ __launch_bounds__(256) void bn_out_kernel(
    const ushort_t* __restrict__ y, const float* __restrict__ ssum, const float* __restrict__ ssq,
    const float* __restrict__ g, const float* __restrict__ beta, float* __restrict__ out)
{
    __shared__ float tile[64][65];
    __shared__ float sc[64], sh[64];
    const float invN = 1.0f / (float)ROWS_;
    const int bid = blockIdx.x;
    const int b  = bid >> 8;
    const int nt = (bid >> 2) & 63;
    const int ot = bid & 3;
    const int t = threadIdx.x;
    if (t < 64) {
        int c = ot * 64 + t;
        float mu  = ssum[c] * invN;
        float var = ssq[c] * invN - mu * mu;
        float s   = rsqrtf(var + 1e-3f) * g[c];
        sc[t] = s;
        sh[t] = beta[c] - mu * s;
    }
    __syncthreads();
    const int n0 = nt * 64, o0 = ot * 64;
    const ushort_t* yb = y + ((size_t)b * N2_ + n0) * H_ + o0;
#pragma unroll
    for (int j = 0; j < 8; ++j) {
        int lin = j * 256 + t;
        int nl = lin >> 5, cu = (lin & 31) * 2;
        uint_t u = *(const uint_t*)&yb[(size_t)nl * H_ + cu];
        tile[nl][cu]     = fmaxf(bf2f((ushort_t)(u & 0xffff)) * sc[cu]     + sh[cu],     0.0f);
        tile[nl][cu + 1] = fmaxf(bf2f((ushort_t)(u >> 16))    * sc[cu + 1] + sh[cu + 1], 0.0f);
    }
    __syncthreads();
    float* ob = out + ((size_t)b * H_ + o0) * N2_ + n0;
#pragma unroll
    for (int j = 0; j < 16; ++j) {
        int lin = j * 256 + t;
        int ol = lin >> 6, nl = lin & 63;
        ob[(size_t)ol * N2_ + nl] = tile[nl][ol];
    }
}

// ----------------------------------------------------------------------------
extern "C" void kernel_launch(void* const* d_in, const int* in_sizes, int n_in,
                              void* d_out, int out_size, void* d_ws, size_t ws_size,
                              hipStream_t stream)
{
    (void)in_sizes; (void)n_in; (void)out_size; (void)ws_size;
    const float* points1   = (const float*)d_in[0];
    const float* points2   = (const float*)d_in[1];
    const float* features1 = (const float*)d_in[2];
    const float* features2 = (const float*)d_in[3];
    const float* skipf     = (const float*)d_in[4];
    const float* W1  = (const float*)d_in[5];
    const float* b1  = (const float*)d_in[6];
    const float* g1  = (const float*)d_in[7];
    const float* be1 = (const float*)d_in[8];
    const float* W2  = (const float*)d_in[9];
    const float* b2  = (const float*)d_in[10];
    const float* g2  = (const float*)d_in[11];
    const float* be2 = (const float*)d_in[12];
    float* out = (float*)d_out;

    char* ws = (char*)d_ws;
    float*    s1  = (float*)(ws + 0);
    float*    q1  = (float*)(ws + 1024);
    float*    s2  = (float*)(ws + 2048);
    float*    q2  = (float*)(ws + 3072);
    int*      ind = (int*)(ws + 4096);                 // 393216 B
    float*    wgt = (float*)(ws + 397312);             // 393216 B
    ushort_t* x   = (ushort_t*)(ws + 790528);          // 29,360,128 B (bf16 32768x448)
    ushort_t* y1b = (ushort_t*)(ws + 30150656);        // 16,777,216 B (bf16 raw y1)
    ushort_t* y1n = (ushort_t*)(ws + 46927872);        // 16,777,216 B (bf16 BN1+ReLU(y1))
    ushort_t* W1b = (ushort_t*)(ws + 63705088);        // 229,376 B
    ushort_t* W2b = (ushort_t*)(ws + 63934464);        // 131,072 B
    ushort_t* f1t = (ushort_t*)(ws + 64065536);        // 4,194,304 B (bf16 8x1024x256)
    ushort_t* y2b = x;                                 // alias: x dead after gemm1

    hipMemsetAsync(ws, 0, 4096, stream);               // zero BN stats

    fused_pre<<<dim3(3008), dim3(256), 0, stream>>>(points1, points2, ind, wgt,
                                                    features1, features2, skipf,
                                                    W1, W2, f1t, x, W1b, W2b);
    gather_x<<<dim3(4096), dim3(256), 0, stream>>>(f1t, ind, wgt, x);

    gemm_bf16<<<dim3(ROWS_ / 128, 4), dim3(256), 0, stream>>>(x, W1b, b1, y1b, s1, q1, CT_);
    bn_relu_mid<<<dim3(256), dim3(256), 0, stream>>>(y1b, s1, q1, g1, be1, y1n);
    gemm_bf16<<<dim3(ROWS_ / 128, 4), dim3(256), 0, stream>>>(y1n, W2b, b2, y2b, s2, q2, H_);
    bn_out_kernel<<<dim3(2048), dim3(256), 0, stream>>>(y2b, s2, q2, g2, be2, out);
}

// Round 10
// 208.586 us; speedup vs baseline: 1.4819x; 1.0312x over previous
//
#include <hip/hip_runtime.h>
#include <cstdint>
#include <cstddef>

#define B_    8
#define N1_   1024
#define N2_   4096
#define C1_   256
#define C2_   128
#define CS_   64
#define CT_   448
#define H_    256
#define ROWS_ (B_ * N2_)   // 32768

typedef __attribute__((ext_vector_type(8))) short bf16x8;
typedef __attribute__((ext_vector_type(4))) float f32x4;
typedef unsigned short ushort_t;
typedef unsigned int   uint_t;

__device__ __forceinline__ ushort_t f2bf(float f) {
    uint_t u = __float_as_uint(f);
    u = (u + 0x7fffu + ((u >> 16) & 1u)) >> 16;   // RNE
    return (ushort_t)u;
}
__device__ __forceinline__ float bf2f(ushort_t h) {
    return __uint_as_float(((uint_t)h) << 16);
}

// ---------------------------------------------------------------- fused KNN + prep
// bid < 1024: KNN, 32 queries x 8 index-ordered splits of 128 candidates.
//   phase 1: fast fma d^2, value-only top-3 (fmin/med3) -> threshold+2e-3 margin
//   phase 2: rescan fast, compact survivor indices (ascending) to LDS lists
//   phase 3: bit-exact R4 arithmetic (contract-off, (s2+ss)-2*dot, sqrt-domain,
//            strict <) on survivors + ascending merge. Selection identical to
//            full exact scan (margin 2e-3 >> 2e-5 worst-case |fast-exact|).
// bid >= 1024: prep (transpose f1 / f2+skip / convert W) — proven code.
__global__ __launch_bounds__(256) void fused_pre(
    const float* __restrict__ p1, const float* __restrict__ p2,
    int* __restrict__ ind, float* __restrict__ wout,
    const float* __restrict__ f1, const float* __restrict__ f2,
    const float* __restrict__ fs, const float* __restrict__ W1,
    const float* __restrict__ W2, ushort_t* __restrict__ f1t,
    ushort_t* __restrict__ x, ushort_t* __restrict__ W1b, ushort_t* __restrict__ W2b)
{
#pragma clang fp contract(off)
    __shared__ __align__(16) char smem[32000];
    const int t = threadIdx.x;
    const int bid = blockIdx.x;
    if (bid < 1024) {
        float4*   cand  = (float4*)(smem);             // 1024 x (x,y,z,|p|^2), 16384 B
        float*    pvals = (float*)(smem + 16512);      // [256][3] fast top-3 vals, 3072 B
        float*    thr   = (float*)(smem + 19584);      // [32], 128 B
        ushort_t* lists = (ushort_t*)(smem + 19712);   // [32][8][12], 6144 B
        float*    pdd   = (float*)(smem + 25856);      // [8][32][3], 3072 B
        int*      pdi   = (int*)(smem + 28928);        // [8][32][3], 3072 B
        const int b  = bid >> 7;                 // 128 blocks per batch
        const int qb = (bid & 127) * 32;         // 32 queries per block
        const float* pb1 = p1 + (size_t)b * 3 * N1_;
        for (int i = t; i < N1_; i += 256) {
            float X = pb1[i], Y = pb1[N1_ + i], Z = pb1[2 * N1_ + i];
            cand[i] = make_float4(X, Y, Z, (X * X + Y * Y) + Z * Z);
        }
        const int q = t & 31, split = t >> 5;
        const int n = qb + q;
        const float* pb2 = p2 + (size_t)b * 3 * N2_;
        const float ax = pb2[n], ay = pb2[N2_ + n], az = pb2[2 * N2_ + n];
        const float s2a = (ax * ax + ay * ay) + az * az;
        const float m2x = -2.0f * ax, m2y = -2.0f * ay, m2z = -2.0f * az;
        __syncthreads();
        // ---- phase 1: fast value-only top-3 over this split (128 cands)
        const int ibeg = split * 128, iend = ibeg + 128;
        {
            float a0 = 3e38f, a1 = 3e38f, a2 = 3e38f;
            for (int i = ibeg; i < iend; ++i) {
                float4 c = cand[i];
                float fd = fmaf(c.x, m2x, fmaf(c.y, m2y, fmaf(c.z, m2z, s2a + c.w)));
                float o0 = a0, o1 = a1;
                a0 = fminf(o0, fd);
                a1 = __builtin_amdgcn_fmed3f(fd, o0, o1);
                a2 = __builtin_amdgcn_fmed3f(fd, o1, a2);
            }
            pvals[t * 3 + 0] = a0; pvals[t * 3 + 1] = a1; pvals[t * 3 + 2] = a2;
        }
        __syncthreads();
        if (t < 32) {
            float m0 = 3e38f, m1 = 3e38f, m2v = 3e38f;
#pragma unroll
            for (int g = 0; g < 8; ++g)
#pragma unroll
                for (int r = 0; r < 3; ++r) {
                    float v = pvals[(g * 32 + t) * 3 + r];
                    float o0 = m0, o1 = m1;
                    m0 = fminf(o0, v);
                    m1 = __builtin_amdgcn_fmed3f(v, o0, o1);
                    m2v = __builtin_amdgcn_fmed3f(v, o1, m2v);
                }
            thr[t] = m2v + 2e-3f;
        }
        __syncthreads();
        // ---- phase 2: compact survivors (ascending index within split)
        const float th = thr[q];
        ushort_t* mylist = lists + (q * 8 + split) * 12;
        int cnt = 0;
        for (int i = ibeg; i < iend; ++i) {
            float4 c = cand[i];
            float fd = fmaf(c.x, m2x, fmaf(c.y, m2y, fmaf(c.z, m2z, s2a + c.w)));
            if (fd <= th && cnt < 12) { mylist[cnt] = (ushort_t)i; cnt++; }
        }
        // ---- phase 3a: exact top-3 over survivors (R4-proven arithmetic)
        float e0 = 3e38f, e1 = 3e38f, e2 = 3e38f;
        int   j0 = 0, j1 = 0, j2 = 0;
        for (int k = 0; k < cnt; ++k) {
            const int i = mylist[k];
            float4 c = cand[i];
            float dot = (ax * c.x + ay * c.y) + az * c.z;
            float dd  = (s2a + c.w) - 2.0f * dot;
            float d   = sqrtf(fmaxf(dd, 0.0f));
            if (d < e0)      { e2 = e1; j2 = j1; e1 = e0; j1 = j0; e0 = d; j0 = i; }
            else if (d < e1) { e2 = e1; j2 = j1; e1 = d;  j1 = i; }
            else if (d < e2) { e2 = d;  j2 = i; }
        }
        pdd[(split * 32 + q) * 3 + 0] = e0; pdi[(split * 32 + q) * 3 + 0] = j0;
        pdd[(split * 32 + q) * 3 + 1] = e1; pdi[(split * 32 + q) * 3 + 1] = j1;
        pdd[(split * 32 + q) * 3 + 2] = e2; pdi[(split * 32 + q) * 3 + 2] = j2;
        __syncthreads();
        // ---- phase 3b: merge splits in ascending order (proven semantics)
        if (t < 32) {
            float f0 = 3e38f, f1v = 3e38f, f2v = 3e38f;
            int   k0 = 0, k1 = 0, k2 = 0;
#pragma unroll
            for (int g = 0; g < 8; ++g)
#pragma unroll
                for (int r = 0; r < 3; ++r) {
                    float d = pdd[(g * 32 + t) * 3 + r];
                    int   i = pdi[(g * 32 + t) * 3 + r];
                    if (d < f0)       { f2v = f1v; k2 = k1; f1v = f0; k1 = k0; f0 = d; k0 = i; }
                    else if (d < f1v) { f2v = f1v; k2 = k1; f1v = d;  k1 = i; }
                    else if (d < f2v) { f2v = d;  k2 = i; }
                }
            float inv0 = 1.0f / (f0 + 1e-10f);
            float inv1 = 1.0f / (f1v + 1e-10f);
            float inv2 = 1.0f / (f2v + 1e-10f);
            float s = (inv0 + inv1) + inv2;
            const size_t row = (size_t)b * N2_ + qb + t;
            wout[row * 3 + 0] = inv0 / s;
            wout[row * 3 + 1] = inv1 / s;
            wout[row * 3 + 2] = inv2 / s;
            ind[row * 3 + 0] = k0;
            ind[row * 3 + 1] = k1;
            ind[row * 3 + 2] = k2;
        }
    } else if (bid < 1536) {                 // transpose f1 -> f1t [B,N1,C1] bf16
        float (*tile)[65] = (float (*)[65])smem;
        const int bid2 = bid - 1024;
        const int b  = bid2 >> 6;
        const int ct = (bid2 >> 4) & 3;
        const int nt = bid2 & 15;
        const int c0 = ct * 64, n0 = nt * 64;
        const float* src = f1 + ((size_t)b * C1_ + c0) * N1_ + n0;
#pragma unroll
        for (int j = 0; j < 16; ++j) {
            int lin = j * 256 + t;
            int ci = lin >> 6, nj = lin & 63;
            tile[ci][nj] = src[(size_t)ci * N1_ + nj];
        }
        __syncthreads();
        ushort_t* dst = f1t + ((size_t)b * N1_ + n0) * C1_ + c0;
#pragma unroll
        for (int j = 0; j < 8; ++j) {
            int lin = j * 256 + t;
            int ni = lin >> 5, cjp = (lin & 31) * 2;
            uint_t u = (uint_t)f2bf(tile[cjp][ni]) | ((uint_t)f2bf(tile[cjp + 1][ni]) << 16);
            *(uint_t*)&dst[(size_t)ni * C1_ + cjp] = u;
        }
    } else if (bid < 3072) {                 // transpose f2/skip -> x tail cols
        float (*tile)[65] = (float (*)[65])smem;
        const int bid2 = bid - 1536;
        const int b   = bid2 / 192;
        const int rem = bid2 - b * 192;
        const int ct  = rem >> 6;
        const int nt  = rem & 63;
        const float* src;
        int coff;
        if (ct < 2) { src = f2 + ((size_t)b * C2_ + ct * 64) * N2_; coff = C1_ + ct * 64; }
        else        { src = fs + (size_t)b * CS_ * N2_;             coff = C1_ + C2_; }
        const int n0 = nt * 64;
#pragma unroll
        for (int j = 0; j < 16; ++j) {
            int lin = j * 256 + t;
            int ci = lin >> 6, nj = lin & 63;
            tile[ci][nj] = src[(size_t)ci * N2_ + n0 + nj];
        }
        __syncthreads();
#pragma unroll
        for (int j = 0; j < 8; ++j) {
            int lin = j * 256 + t;
            int ni = lin >> 5, cjp = (lin & 31) * 2;
            uint_t u = (uint_t)f2bf(tile[cjp][ni]) | ((uint_t)f2bf(tile[cjp + 1][ni]) << 16);
            *(uint_t*)&x[((size_t)b * N2_ + n0 + ni) * CT_ + coff + cjp] = u;
        }
    } else {                                 // convert W1/W2 -> bf16
        const int i = (bid - 3072) * 256 + t;
        if (i < H_ * CT_) W1b[i] = f2bf(W1[i]);
        if (i < H_ * H_)  W2b[i] = f2bf(W2[i]);
    }
}

// ------------------------------- gather+interp -> x_bf16[:, 0:256]
__global__ __launch_bounds__(256) void gather_x(
    const ushort_t* __restrict__ f1t, const int* __restrict__ ind,
    const float* __restrict__ w, ushort_t* __restrict__ x)
{
    const int t = threadIdx.x;
    const int row = blockIdx.x * 8 + (t >> 5);
    const int b = row >> 12;
    const int cg = (t & 31) * 8;
    const int*   ip = ind + (size_t)row * 3;
    const float* wp = w   + (size_t)row * 3;
    const int i0 = ip[0], i1 = ip[1], i2 = ip[2];
    const float w0 = wp[0], w1 = wp[1], w2 = wp[2];
    const ushort_t* base = f1t + (size_t)b * N1_ * C1_;
    uint4 va = *(const uint4*)(base + (size_t)i0 * C1_ + cg);
    uint4 vb = *(const uint4*)(base + (size_t)i1 * C1_ + cg);
    uint4 vc = *(const uint4*)(base + (size_t)i2 * C1_ + cg);
    const uint_t* pa = (const uint_t*)&va;
    const uint_t* pb = (const uint_t*)&vb;
    const uint_t* pc = (const uint_t*)&vc;
    uint_t out[4];
#pragma unroll
    for (int e = 0; e < 4; ++e) {
        float lo = w0 * bf2f((ushort_t)(pa[e] & 0xffff))
                 + w1 * bf2f((ushort_t)(pb[e] & 0xffff))
                 + w2 * bf2f((ushort_t)(pc[e] & 0xffff));
        float hi = w0 * bf2f((ushort_t)(pa[e] >> 16))
                 + w1 * bf2f((ushort_t)(pb[e] >> 16))
                 + w2 * bf2f((ushort_t)(pc[e] >> 16));
        out[e] = (uint_t)f2bf(lo) | ((uint_t)f2bf(hi) << 16);
    }
    *(uint4*)&x[(size_t)row * CT_ + cg] = *(uint4*)out;
}

// ------------------------------- bf16 GEMM (both layers) — R8-proven core.
// 1D grid, m-major swizzle: bid = m_tile*4 + n_tile, so the 4 n-tiles sharing
// an A m-tile are dispatch-adjacent (concurrent) -> A re-reads hit L2/L3 hot.
__global__ __launch_bounds__(256, 4) void gemm_bf16(
    const ushort_t* __restrict__ A, const ushort_t* __restrict__ Bw,
    const float* __restrict__ bias, ushort_t* __restrict__ C,
    float* __restrict__ ssum, float* __restrict__ ssq, int K)
{
    __shared__ __align__(16) ushort_t smem[128 * 72];   // 18.4 KB union
    ushort_t* As = smem;                 // 128 x 40
    ushort_t* Bs = smem + 5120;          //  64 x 40
    ushort_t* Cs = smem;                 // 128 x 72 epilogue tile (reuse)
    const int t = threadIdx.x;
    const int m0 = (blockIdx.x >> 2) * 128;
    const int n0 = (blockIdx.x & 3) * 64;
    const int lane = t & 63;
    const int wv = t >> 6;
    const int wrow = wv & 1, wcol = wv >> 1;
    const int lm = lane & 15, lq = lane >> 4;
    const int crow = t >> 2, ckc = (t & 3) * 8;
    f32x4 acc[4][2];
#pragma unroll
    for (int i = 0; i < 4; ++i)
#pragma unroll
        for (int j = 0; j < 2; ++j)
            acc[i][j] = (f32x4){0.f, 0.f, 0.f, 0.f};

    for (int k0 = 0; k0 < K; k0 += 32) {
        uint4 a0 = *(const uint4*)(A  + (size_t)(m0 + crow) * K + k0 + ckc);
        uint4 a1 = *(const uint4*)(A  + (size_t)(m0 + 64 + crow) * K + k0 + ckc);
        uint4 b0 = *(const uint4*)(Bw + (size_t)(n0 + crow) * K + k0 + ckc);
        __syncthreads();
        *(uint4*)&As[crow * 40 + ckc]        = a0;
        *(uint4*)&As[(64 + crow) * 40 + ckc] = a1;
        *(uint4*)&Bs[crow * 40 + ckc]        = b0;
        __syncthreads();
        bf16x8 af[4], bfr[2];
#pragma unroll
        for (int i = 0; i < 4; ++i)
            af[i] = *(const bf16x8*)&As[(wrow * 64 + i * 16 + lm) * 40 + lq * 8];
#pragma unroll
        for (int j = 0; j < 2; ++j)
            bfr[j] = *(const bf16x8*)&Bs[(wcol * 32 + j * 16 + lm) * 40 + lq * 8];
#pragma unroll
        for (int i = 0; i < 4; ++i)
#pragma unroll
            for (int j = 0; j < 2; ++j)
                acc[i][j] = __builtin_amdgcn_mfma_f32_16x16x32_bf16(af[i], bfr[j], acc[i][j], 0, 0, 0);
    }
    __syncthreads();
#pragma unroll
    for (int j = 0; j < 2; ++j) {
        const int gn_l = wcol * 32 + j * 16 + lm;
        const int gn   = n0 + gn_l;
        const float bb = bias[gn];
        float ps = 0.0f, pq = 0.0f;
#pragma unroll
        for (int i = 0; i < 4; ++i) {
            const int row_l = wrow * 64 + i * 16 + lq * 4;
            f32x4 v = acc[i][j];
#pragma unroll
            for (int r = 0; r < 4; ++r) {
                float val = v[r] + bb;
                ps += val;
                pq += val * val;
                float vo = __shfl_xor(val, 1);
                uint_t packed = (lm & 1)
                    ? ((uint_t)f2bf(vo)  | ((uint_t)f2bf(val) << 16))
                    : ((uint_t)f2bf(val) | ((uint_t)f2bf(vo)  << 16));
                if ((lm & 1) == 0)
                    *(uint_t*)&Cs[(row_l + r) * 72 + (gn_l & ~1)] = packed;
            }
        }
        ps += __shfl_xor(ps, 16); pq += __shfl_xor(pq, 16);
        ps += __shfl_xor(ps, 32); pq += __shfl_xor(pq, 32);
        if (lane < 16) {
            atomicAdd(&ssum[gn], ps);
            atomicAdd(&ssq[gn], pq);
        }
    }
    __syncthreads();
    const int srow = t >> 3;
    const int scol = (t & 7) * 8;
#pragma unroll
    for (int rep = 0; rep < 4; ++rep) {
        const int row = srow + rep * 32;
        uint4 v = *(const uint4*)&Cs[row * 72 + scol];
        *(uint4*)(C + (size_t)(m0 + row) * H_ + n0 + scol) = v;
    }
}

// ------------------------------- BN1 + ReLU: y1b (bf16, raw) -> y1n (bf16, normalized)
__global__ __launch_bounds__(256) void bn_relu_mid(
    const ushort_t* __restrict__ y, const float* __restrict__ ssum,
    const float* __restrict__ ssq, const float* __restrict__ g,
    const float* __restrict__ beta, ushort_t* __restrict__ yn)
{
    __shared__ float sc[H_], sh[H_];
    const int t = threadIdx.x;
    {
        const float invN = 1.0f / (float)ROWS_;
        float mu  = ssum[t] * invN;
        float var = ssq[t] * invN - mu * mu;
        float s   = rsqrtf(var + 1e-3f) * g[t];
        sc[t] = s;
        sh[t] = beta[t] - mu * s;
    }
    __syncthreads();
    const int c0 = (t & 31) * 8;
    float s[8], h[8];
#pragma unroll
    for (int e = 0; e < 8; ++e) { s[e] = sc[c0 + e]; h[e] = sh[c0 + e]; }
    const uint4* yin = (const uint4*)y;
    uint4* yout = (uint4*)yn;
    const size_t base = (size_t)blockIdx.x * 2048 + t;
#pragma unroll
    for (int j = 0; j < 8; ++j) {
        uint4 u = yin[base + j * 256];
        uint_t* uw = (uint_t*)&u;
        uint_t o[4];
#pragma unroll
        for (int e = 0; e < 4; ++e) {
            float lo = __uint_as_float(uw[e] << 16);
            float hi = __uint_as_float(uw[e] & 0xffff0000u);
            float rlo = fmaxf(fmaf(lo, s[2 * e],     h[2 * e]),     0.0f);
            float rhi = fmaxf(fmaf(hi, s[2 * e + 1], h[2 * e + 1]), 0.0f);
            o[e] = (uint_t)f2bf(rlo) | ((uint_t)f2bf(rhi) << 16);
        }
        yout[base + j * 256] = *(uint4*)o;
    }
}

// ------------------------------- BN2 + ReLU + transpose, bf16 y2 -> out[B,256,N2] fp32
__global__ __launch_bounds__(256) void bn_out_kernel(
    const ushort_t* __restrict__ y, const float* __restrict__ ssum, const float* __restrict__ ssq,
    const float* __restrict__ g, const float* __restrict__ beta, float* __restrict__ out)
{
    __shared__ float tile[64][65];
    __shared__ float sc[64], sh[64];
    const float invN = 1.0f / (float)ROWS_;
    const int bid = blockIdx.x;
    const int b  = bid >> 8;
    const int nt = (bid >> 2) & 63;
    const int ot = bid & 3;
    const int t = threadIdx.x;
    if (t < 64) {
        int c = ot * 64 + t;
        float mu  = ssum[c] * invN;
        float var = ssq[c] * invN - mu * mu;
        float s   = rsqrtf(var + 1e-3f) * g[c];
        sc[t] = s;
        sh[t] = beta[c] - mu * s;
    }
    __syncthreads();
    const int n0 = nt * 64, o0 = ot * 64;
    const ushort_t* yb = y + ((size_t)b * N2_ + n0) * H_ + o0;
#pragma unroll
    for (int j = 0; j < 8; ++j) {
        int lin = j * 256 + t;
        int nl = lin >> 5, cu = (lin & 31) * 2;
        uint_t u = *(const uint_t*)&yb[(size_t)nl * H_ + cu];
        tile[nl][cu]     = fmaxf(bf2f((ushort_t)(u & 0xffff)) * sc[cu]     + sh[cu],     0.0f);
        tile[nl][cu + 1] = fmaxf(bf2f((ushort_t)(u >> 16))    * sc[cu + 1] + sh[cu + 1], 0.0f);
    }
    __syncthreads();
    float* ob = out + ((size_t)b * H_ + o0) * N2_ + n0;
#pragma unroll
    for (int j = 0; j < 16; ++j) {
        int lin = j * 256 + t;
        int ol = lin >> 6, nl = lin & 63;
        ob[(size_t)ol * N2_ + nl] = tile[nl][ol];
    }
}

// ----------------------------------------------------------------------------
extern "C" void kernel_launch(void* const* d_in, const int* in_sizes, int n_in,
                              void* d_out, int out_size, void* d_ws, size_t ws_size,
                              hipStream_t stream)
{
    (void)in_sizes; (void)n_in; (void)out_size; (void)ws_size;
    const float* points1   = (const float*)d_in[0];
    const float* points2   = (const float*)d_in[1];
    const float* features1 = (const float*)d_in[2];
    const float* features2 = (const float*)d_in[3];
    const float* skipf     = (const float*)d_in[4];
    const float* W1  = (const float*)d_in[5];
    const float* b1  = (const float*)d_in[6];
    const float* g1  = (const float*)d_in[7];
    const float* be1 = (const float*)d_in[8];
    const float* W2  = (const float*)d_in[9];
    const float* b2  = (const float*)d_in[10];
    const float* g2  = (const float*)d_in[11];
    const float* be2 = (const float*)d_in[12];
    float* out = (float*)d_out;

    char* ws = (char*)d_ws;
    float*    s1  = (float*)(ws + 0);
    float*    q1  = (float*)(ws + 1024);
    float*    s2  = (float*)(ws + 2048);
    float*    q2  = (float*)(ws + 3072);
    int*      ind = (int*)(ws + 4096);                 // 393216 B
    float*    wgt = (float*)(ws + 397312);             // 393216 B
    ushort_t* x   = (ushort_t*)(ws + 790528);          // 29,360,128 B (bf16 32768x448)
    ushort_t* y1b = (ushort_t*)(ws + 30150656);        // 16,777,216 B (bf16 raw y1)
    ushort_t* y1n = (ushort_t*)(ws + 46927872);        // 16,777,216 B (bf16 BN1+ReLU(y1))
    ushort_t* W1b = (ushort_t*)(ws + 63705088);        // 229,376 B
    ushort_t* W2b = (ushort_t*)(ws + 63934464);        // 131,072 B
    ushort_t* f1t = (ushort_t*)(ws + 64065536);        // 4,194,304 B (bf16 8x1024x256)
    ushort_t* y2b = x;                                 // alias: x dead after gemm1

    hipMemsetAsync(ws, 0, 4096, stream);               // zero BN stats

    fused_pre<<<dim3(3520), dim3(256), 0, stream>>>(points1, points2, ind, wgt,
                                                    features1, features2, skipf,
                                                    W1, W2, f1t, x, W1b, W2b);
    gather_x<<<dim3(4096), dim3(256), 0, stream>>>(f1t, ind, wgt, x);

    gemm_bf16<<<dim3(ROWS_ / 128 * 4), dim3(256), 0, stream>>>(x, W1b, b1, y1b, s1, q1, CT_);
    bn_relu_mid<<<dim3(512), dim3(256), 0, stream>>>(y1b, s1, q1, g1, be1, y1n);
    gemm_bf16<<<dim3(ROWS_ / 128 * 4), dim3(256), 0, stream>>>(y1n, W2b, b2, y2b, s2, q2, H_);
    bn_out_kernel<<<dim3(2048), dim3(256), 0, stream>>>(y2b, s2, q2, g2, be2, out);
}

// Round 11
// 205.029 us; speedup vs baseline: 1.5076x; 1.0173x over previous
//
#include <hip/hip_runtime.h>
#include <cstdint>
#include <cstddef>

#define B_    8
#define N1_   1024
#define N2_   4096
#define C1_   256
#define C2_   128
#define CS_   64
#define CT_   448
#define H_    256
#define ROWS_ (B_ * N2_)   // 32768

typedef __attribute__((ext_vector_type(8))) short bf16x8;
typedef __attribute__((ext_vector_type(4))) float f32x4;
typedef unsigned short ushort_t;
typedef unsigned int   uint_t;

__device__ __forceinline__ ushort_t f2bf(float f) {
    uint_t u = __float_as_uint(f);
    u = (u + 0x7fffu + ((u >> 16) & 1u)) >> 16;   // RNE
    return (ushort_t)u;
}
__device__ __forceinline__ float bf2f(ushort_t h) {
    return __uint_as_float(((uint_t)h) << 16);
}
// async global->LDS, 16B per lane; LDS dst = wave-uniform base + lane*16
__device__ __forceinline__ void glds16(const void* g, void* l) {
    __builtin_amdgcn_global_load_lds(
        (const __attribute__((address_space(1))) void*)g,
        (__attribute__((address_space(3))) void*)l, 16, 0, 0);
}

// ---------------------------------------------------------------- fused KNN + prep
// (unchanged from R10 — proven)
__global__ __launch_bounds__(256) void fused_pre(
    const float* __restrict__ p1, const float* __restrict__ p2,
    int* __restrict__ ind, float* __restrict__ wout,
    const float* __restrict__ f1, const float* __restrict__ f2,
    const float* __restrict__ fs, const float* __restrict__ W1,
    const float* __restrict__ W2, ushort_t* __restrict__ f1t,
    ushort_t* __restrict__ x, ushort_t* __restrict__ W1b, ushort_t* __restrict__ W2b)
{
#pragma clang fp contract(off)
    __shared__ __align__(16) char smem[32000];
    const int t = threadIdx.x;
    const int bid = blockIdx.x;
    if (bid < 1024) {
        float4*   cand  = (float4*)(smem);
        float*    pvals = (float*)(smem + 16512);
        float*    thr   = (float*)(smem + 19584);
        ushort_t* lists = (ushort_t*)(smem + 19712);
        float*    pdd   = (float*)(smem + 25856);
        int*      pdi   = (int*)(smem + 28928);
        const int b  = bid >> 7;
        const int qb = (bid & 127) * 32;
        const float* pb1 = p1 + (size_t)b * 3 * N1_;
        for (int i = t; i < N1_; i += 256) {
            float X = pb1[i], Y = pb1[N1_ + i], Z = pb1[2 * N1_ + i];
            cand[i] = make_float4(X, Y, Z, (X * X + Y * Y) + Z * Z);
        }
        const int q = t & 31, split = t >> 5;
        const int n = qb + q;
        const float* pb2 = p2 + (size_t)b * 3 * N2_;
        const float ax = pb2[n], ay = pb2[N2_ + n], az = pb2[2 * N2_ + n];
        const float s2a = (ax * ax + ay * ay) + az * az;
        const float m2x = -2.0f * ax, m2y = -2.0f * ay, m2z = -2.0f * az;
        __syncthreads();
        const int ibeg = split * 128, iend = ibeg + 128;
        {
            float a0 = 3e38f, a1 = 3e38f, a2 = 3e38f;
            for (int i = ibeg; i < iend; ++i) {
                float4 c = cand[i];
                float fd = fmaf(c.x, m2x, fmaf(c.y, m2y, fmaf(c.z, m2z, s2a + c.w)));
                float o0 = a0, o1 = a1;
                a0 = fminf(o0, fd);
                a1 = __builtin_amdgcn_fmed3f(fd, o0, o1);
                a2 = __builtin_amdgcn_fmed3f(fd, o1, a2);
            }
            pvals[t * 3 + 0] = a0; pvals[t * 3 + 1] = a1; pvals[t * 3 + 2] = a2;
        }
        __syncthreads();
        if (t < 32) {
            float m0 = 3e38f, m1 = 3e38f, m2v = 3e38f;
#pragma unroll
            for (int g = 0; g < 8; ++g)
#pragma unroll
                for (int r = 0; r < 3; ++r) {
                    float v = pvals[(g * 32 + t) * 3 + r];
                    float o0 = m0, o1 = m1;
                    m0 = fminf(o0, v);
                    m1 = __builtin_amdgcn_fmed3f(v, o0, o1);
                    m2v = __builtin_amdgcn_fmed3f(v, o1, m2v);
                }
            thr[t] = m2v + 2e-3f;
        }
        __syncthreads();
        const float th = thr[q];
        ushort_t* mylist = lists + (q * 8 + split) * 12;
        int cnt = 0;
        for (int i = ibeg; i < iend; ++i) {
            float4 c = cand[i];
            float fd = fmaf(c.x, m2x, fmaf(c.y, m2y, fmaf(c.z, m2z, s2a + c.w)));
            if (fd <= th && cnt < 12) { mylist[cnt] = (ushort_t)i; cnt++; }
        }
        float e0 = 3e38f, e1 = 3e38f, e2 = 3e38f;
        int   j0 = 0, j1 = 0, j2 = 0;
        for (int k = 0; k < cnt; ++k) {
            const int i = mylist[k];
            float4 c = cand[i];
            float dot = (ax * c.x + ay * c.y) + az * c.z;
            float dd  = (s2a + c.w) - 2.0f * dot;
            float d   = sqrtf(fmaxf(dd, 0.0f));
            if (d < e0)      { e2 = e1; j2 = j1; e1 = e0; j1 = j0; e0 = d; j0 = i; }
            else if (d < e1) { e2 = e1; j2 = j1; e1 = d;  j1 = i; }
            else if (d < e2) { e2 = d;  j2 = i; }
        }
        pdd[(split * 32 + q) * 3 + 0] = e0; pdi[(split * 32 + q) * 3 + 0] = j0;
        pdd[(split * 32 + q) * 3 + 1] = e1; pdi[(split * 32 + q) * 3 + 1] = j1;
        pdd[(split * 32 + q) * 3 + 2] = e2; pdi[(split * 32 + q) * 3 + 2] = j2;
        __syncthreads();
        if (t < 32) {
            float f0 = 3e38f, f1v = 3e38f, f2v = 3e38f;
            int   k0 = 0, k1 = 0, k2 = 0;
#pragma unroll
            for (int g = 0; g < 8; ++g)
#pragma unroll
                for (int r = 0; r < 3; ++r) {
                    float d = pdd[(g * 32 + t) * 3 + r];
                    int   i = pdi[(g * 32 + t) * 3 + r];
                    if (d < f0)       { f2v = f1v; k2 = k1; f1v = f0; k1 = k0; f0 = d; k0 = i; }
                    else if (d < f1v) { f2v = f1v; k2 = k1; f1v = d;  k1 = i; }
                    else if (d < f2v) { f2v = d;  k2 = i; }
                }
            float inv0 = 1.0f / (f0 + 1e-10f);
            float inv1 = 1.0f / (f1v + 1e-10f);
            float inv2 = 1.0f / (f2v + 1e-10f);
            float s = (inv0 + inv1) + inv2;
            const size_t row = (size_t)b * N2_ + qb + t;
            wout[row * 3 + 0] = inv0 / s;
            wout[row * 3 + 1] = inv1 / s;
            wout[row * 3 + 2] = inv2 / s;
            ind[row * 3 + 0] = k0;
            ind[row * 3 + 1] = k1;
            ind[row * 3 + 2] = k2;
        }
    } else if (bid < 1536) {
        float (*tile)[65] = (float (*)[65])smem;
        const int bid2 = bid - 1024;
        const int b  = bid2 >> 6;
        const int ct = (bid2 >> 4) & 3;
        const int nt = bid2 & 15;
        const int c0 = ct * 64, n0 = nt * 64;
        const float* src = f1 + ((size_t)b * C1_ + c0) * N1_ + n0;
#pragma unroll
        for (int j = 0; j < 16; ++j) {
            int lin = j * 256 + t;
            int ci = lin >> 6, nj = lin & 63;
            tile[ci][nj] = src[(size_t)ci * N1_ + nj];
        }
        __syncthreads();
        ushort_t* dst = f1t + ((size_t)b * N1_ + n0) * C1_ + c0;
#pragma unroll
        for (int j = 0; j < 8; ++j) {
            int lin = j * 256 + t;
            int ni = lin >> 5, cjp = (lin & 31) * 2;
            uint_t u = (uint_t)f2bf(tile[cjp][ni]) | ((uint_t)f2bf(tile[cjp + 1][ni]) << 16);
            *(uint_t*)&dst[(size_t)ni * C1_ + cjp] = u;
        }
    } else if (bid < 3072) {
        float (*tile)[65] = (float (*)[65])smem;
        const int bid2 = bid - 1536;
        const int b   = bid2 / 192;
        const int rem = bid2 - b * 192;
        const int ct  = rem >> 6;
        const int nt  = rem & 63;
        const float* src;
        int coff;
        if (ct < 2) { src = f2 + ((size_t)b * C2_ + ct * 64) * N2_; coff = C1_ + ct * 64; }
        else        { src = fs + (size_t)b * CS_ * N2_;             coff = C1_ + C2_; }
        const int n0 = nt * 64;
#pragma unroll
        for (int j = 0; j < 16; ++j) {
            int lin = j * 256 + t;
            int ci = lin >> 6, nj = lin & 63;
            tile[ci][nj] = src[(size_t)ci * N2_ + n0 + nj];
        }
        __syncthreads();
#pragma unroll
        for (int j = 0; j < 8; ++j) {
            int lin = j * 256 + t;
            int ni = lin >> 5, cjp = (lin & 31) * 2;
            uint_t u = (uint_t)f2bf(tile[cjp][ni]) | ((uint_t)f2bf(tile[cjp + 1][ni]) << 16);
            *(uint_t*)&x[((size_t)b * N2_ + n0 + ni) * CT_ + coff + cjp] = u;
        }
    } else {
        const int i = (bid - 3072) * 256 + t;
        if (i < H_ * CT_) W1b[i] = f2bf(W1[i]);
        if (i < H_ * H_)  W2b[i] = f2bf(W2[i]);
    }
}

// ------------------------------- gather+interp -> x_bf16[:, 0:256] (unchanged)
__global__ __launch_bounds__(256) void gather_x(
    const ushort_t* __restrict__ f1t, const int* __restrict__ ind,
    const float* __restrict__ w, ushort_t* __restrict__ x)
{
    const int t = threadIdx.x;
    const int row = blockIdx.x * 8 + (t >> 5);
    const int b = row >> 12;
    const int cg = (t & 31) * 8;
    const int*   ip = ind + (size_t)row * 3;
    const float* wp = w   + (size_t)row * 3;
    const int i0 = ip[0], i1 = ip[1], i2 = ip[2];
    const float w0 = wp[0], w1 = wp[1], w2 = wp[2];
    const ushort_t* base = f1t + (size_t)b * N1_ * C1_;
    uint4 va = *(const uint4*)(base + (size_t)i0 * C1_ + cg);
    uint4 vb = *(const uint4*)(base + (size_t)i1 * C1_ + cg);
    uint4 vc = *(const uint4*)(base + (size_t)i2 * C1_ + cg);
    const uint_t* pa = (const uint_t*)&va;
    const uint_t* pb = (const uint_t*)&vb;
    const uint_t* pc = (const uint_t*)&vc;
    uint_t out[4];
#pragma unroll
    for (int e = 0; e < 4; ++e) {
        float lo = w0 * bf2f((ushort_t)(pa[e] & 0xffff))
                 + w1 * bf2f((ushort_t)(pb[e] & 0xffff))
                 + w2 * bf2f((ushort_t)(pc[e] & 0xffff));
        float hi = w0 * bf2f((ushort_t)(pa[e] >> 16))
                 + w1 * bf2f((ushort_t)(pb[e] >> 16))
                 + w2 * bf2f((ushort_t)(pc[e] >> 16));
        out[e] = (uint_t)f2bf(lo) | ((uint_t)f2bf(hi) << 16);
    }
    *(uint4*)&x[(size_t)row * CT_ + cg] = *(uint4*)out;
}

// ------------------------------- GEMM1: global_load_lds staging, swizzled LDS.
// LDS slot (row, c) holds global chunk c ^ ((row>>1)&3)  — conflict-free b128
// reads, and glds's lane*16B dst maps exactly onto the unpadded 64B rows.
// Epilogue (Cs union, full-line stores, fused stats) — R8-proven.
__global__ __launch_bounds__(256, 4) void gemm1_glds(
    const ushort_t* __restrict__ A, const ushort_t* __restrict__ Bw,
    const float* __restrict__ bias, ushort_t* __restrict__ C,
    float* __restrict__ ssum, float* __restrict__ ssq)
{
    __shared__ __align__(16) ushort_t smem[128 * 72];   // 18.4 KB
    ushort_t* As = smem;            // 128 x 32, unpadded, swizzled
    ushort_t* Bs = smem + 4096;     //  64 x 32, unpadded, swizzled
    ushort_t* Cs = smem;            // epilogue reuse
    const int t = threadIdx.x;
    const int m0 = (blockIdx.x >> 2) * 128;
    const int n0 = (blockIdx.x & 3) * 64;
    const int lane = t & 63;
    const int wv = t >> 6;
    const int wrow = wv & 1, wcol = wv >> 1;
    const int lm = lane & 15, lq = lane >> 4;
    const int lrow  = lane >> 2;                          // 0..15
    const int gchunk = (lane & 3) ^ ((lane >> 3) & 3);    // swizzled source chunk
    const int csw = (lm >> 1) & 3;                        // read-side swizzle
    const ushort_t* gA0 = A  + (size_t)(m0 + wv * 16 + lrow) * CT_ + gchunk * 8;
    const ushort_t* gA1 = A  + (size_t)(m0 + 64 + wv * 16 + lrow) * CT_ + gchunk * 8;
    const ushort_t* gB  = Bw + (size_t)(n0 + wv * 16 + lrow) * CT_ + gchunk * 8;
    ushort_t* lA0 = As + wv * 512;
    ushort_t* lA1 = As + 2048 + wv * 512;
    ushort_t* lB  = Bs + wv * 512;
    f32x4 acc[4][2];
#pragma unroll
    for (int i = 0; i < 4; ++i)
#pragma unroll
        for (int j = 0; j < 2; ++j)
            acc[i][j] = (f32x4){0.f, 0.f, 0.f, 0.f};

    for (int k0 = 0; k0 < CT_; k0 += 32) {
        __syncthreads();                  // previous iter's LDS reads complete
        glds16(gA0 + k0, lA0);
        glds16(gA1 + k0, lA1);
        glds16(gB  + k0, lB);
        __syncthreads();                  // drains vmcnt -> data in LDS
        bf16x8 af[4], bfr[2];
#pragma unroll
        for (int i = 0; i < 4; ++i)
            af[i] = *(const bf16x8*)&As[(wrow * 64 + i * 16 + lm) * 32 + (lq ^ csw) * 8];
#pragma unroll
        for (int j = 0; j < 2; ++j)
            bfr[j] = *(const bf16x8*)&Bs[(wcol * 32 + j * 16 + lm) * 32 + (lq ^ csw) * 8];
#pragma unroll
        for (int i = 0; i < 4; ++i)
#pragma unroll
            for (int j = 0; j < 2; ++j)
                acc[i][j] = __builtin_amdgcn_mfma_f32_16x16x32_bf16(af[i], bfr[j], acc[i][j], 0, 0, 0);
    }
    __syncthreads();
#pragma unroll
    for (int j = 0; j < 2; ++j) {
        const int gn_l = wcol * 32 + j * 16 + lm;
        const int gn   = n0 + gn_l;
        const float bb = bias[gn];
        float ps = 0.0f, pq = 0.0f;
#pragma unroll
        for (int i = 0; i < 4; ++i) {
            const int row_l = wrow * 64 + i * 16 + lq * 4;
            f32x4 v = acc[i][j];
#pragma unroll
            for (int r = 0; r < 4; ++r) {
                float val = v[r] + bb;
                ps += val;
                pq += val * val;
                float vo = __shfl_xor(val, 1);
                uint_t packed = (lm & 1)
                    ? ((uint_t)f2bf(vo)  | ((uint_t)f2bf(val) << 16))
                    : ((uint_t)f2bf(val) | ((uint_t)f2bf(vo)  << 16));
                if ((lm & 1) == 0)
                    *(uint_t*)&Cs[(row_l + r) * 72 + (gn_l & ~1)] = packed;
            }
        }
        ps += __shfl_xor(ps, 16); pq += __shfl_xor(pq, 16);
        ps += __shfl_xor(ps, 32); pq += __shfl_xor(pq, 32);
        if (lane < 16) {
            atomicAdd(&ssum[gn], ps);
            atomicAdd(&ssq[gn], pq);
        }
    }
    __syncthreads();
    const int srow = t >> 3;
    const int scol = (t & 7) * 8;
#pragma unroll
    for (int rep = 0; rep < 4; ++rep) {
        const int row = srow + rep * 32;
        uint4 v = *(const uint4*)&Cs[row * 72 + scol];
        *(uint4*)(C + (size_t)(m0 + row) * H_ + n0 + scol) = v;
    }
}

// ------------------------------- GEMM2: BN1+ReLU fused into A-staging (bit-identical
// to bn_relu_mid numerics), B via glds+swizzle, padded As for the VALU path.
__global__ __launch_bounds__(256, 4) void gemm2_fused(
    const ushort_t* __restrict__ A, const ushort_t* __restrict__ Bw,
    const float* __restrict__ bias,
    const float* __restrict__ s1, const float* __restrict__ q1,
    const float* __restrict__ g1, const float* __restrict__ be1,
    ushort_t* __restrict__ C, float* __restrict__ ssum, float* __restrict__ ssq)
{
    __shared__ __align__(16) ushort_t smem[128 * 72];   // 18.4 KB
    ushort_t* As = smem;                  // 128 x 40 padded (VALU-staged)
    ushort_t* Bs = smem + 5120;           //  64 x 32 unpadded swizzled (glds)
    float*    sc = (float*)(smem + 7168); // 256 floats
    float*    sh = (float*)(smem + 7680); // 256 floats (ends at byte 16384 < 18432)
    ushort_t* Cs = smem;                  // epilogue reuse (sc/sh dead by then)
    const int t = threadIdx.x;
    const int m0 = (blockIdx.x >> 2) * 128;
    const int n0 = (blockIdx.x & 3) * 64;
    const int lane = t & 63;
    const int wv = t >> 6;
    const int wrow = wv & 1, wcol = wv >> 1;
    const int lm = lane & 15, lq = lane >> 4;
    const int lrow  = lane >> 2;
    const int gchunk = (lane & 3) ^ ((lane >> 3) & 3);
    const int csw = (lm >> 1) & 3;
    const int arow = t >> 1, ahalf = (t & 1) * 16;
    {
        const float invN = 1.0f / (float)ROWS_;
        float mu  = s1[t] * invN;
        float var = q1[t] * invN - mu * mu;
        float s   = rsqrtf(var + 1e-3f) * g1[t];
        sc[t] = s;
        sh[t] = be1[t] - mu * s;
    }
    const ushort_t* gB = Bw + (size_t)(n0 + wv * 16 + lrow) * H_ + gchunk * 8;
    ushort_t* lB = Bs + wv * 512;
    const ushort_t* gA = A + (size_t)(m0 + arow) * H_ + ahalf;
    f32x4 acc[4][2];
#pragma unroll
    for (int i = 0; i < 4; ++i)
#pragma unroll
        for (int j = 0; j < 2; ++j)
            acc[i][j] = (f32x4){0.f, 0.f, 0.f, 0.f};

    for (int k0 = 0; k0 < H_; k0 += 32) {
        uint4 a0 = *(const uint4*)(gA + k0);       // issued before barrier (overlap)
        uint4 a1 = *(const uint4*)(gA + k0 + 8);
        __syncthreads();                  // prev reads done; sc/sh visible (1st iter)
        glds16(gB + k0, lB);
        {
            const uint_t* w0 = (const uint_t*)&a0;
            const uint_t* w1 = (const uint_t*)&a1;
            uint_t o0[4], o1[4];
#pragma unroll
            for (int e = 0; e < 4; ++e) {
                const int cb0 = k0 + ahalf + 2 * e;
                const int cb1 = cb0 + 8;
                float lo0 = __uint_as_float(w0[e] << 16);
                float hi0 = __uint_as_float(w0[e] & 0xffff0000u);
                float lo1 = __uint_as_float(w1[e] << 16);
                float hi1 = __uint_as_float(w1[e] & 0xffff0000u);
                float r0 = fmaxf(fmaf(lo0, sc[cb0],     sh[cb0]),     0.0f);
                float r1 = fmaxf(fmaf(hi0, sc[cb0 + 1], sh[cb0 + 1]), 0.0f);
                float r2 = fmaxf(fmaf(lo1, sc[cb1],     sh[cb1]),     0.0f);
                float r3 = fmaxf(fmaf(hi1, sc[cb1 + 1], sh[cb1 + 1]), 0.0f);
                o0[e] = (uint_t)f2bf(r0) | ((uint_t)f2bf(r1) << 16);
                o1[e] = (uint_t)f2bf(r2) | ((uint_t)f2bf(r3) << 16);
            }
            *(uint4*)&As[arow * 40 + ahalf]     = *(uint4*)o0;
            *(uint4*)&As[arow * 40 + ahalf + 8] = *(uint4*)o1;
        }
        __syncthreads();                  // drains vmcnt (B) + lgkm (As)
        bf16x8 af[4], bfr[2];
#pragma unroll
        for (int i = 0; i < 4; ++i)
            af[i] = *(const bf16x8*)&As[(wrow * 64 + i * 16 + lm) * 40 + lq * 8];
#pragma unroll
        for (int j = 0; j < 2; ++j)
            bfr[j] = *(const bf16x8*)&Bs[(wcol * 32 + j * 16 + lm) * 32 + (lq ^ csw) * 8];
#pragma unroll
        for (int i = 0; i < 4; ++i)
#pragma unroll
            for (int j = 0; j < 2; ++j)
                acc[i][j] = __builtin_amdgcn_mfma_f32_16x16x32_bf16(af[i], bfr[j], acc[i][j], 0, 0, 0);
    }
    __syncthreads();
#pragma unroll
    for (int j = 0; j < 2; ++j) {
        const int gn_l = wcol * 32 + j * 16 + lm;
        const int gn   = n0 + gn_l;
        const float bb = bias[gn];
        float ps = 0.0f, pq = 0.0f;
#pragma unroll
        for (int i = 0; i < 4; ++i) {
            const int row_l = wrow * 64 + i * 16 + lq * 4;
            f32x4 v = acc[i][j];
#pragma unroll
            for (int r = 0; r < 4; ++r) {
                float val = v[r] + bb;
                ps += val;
                pq += val * val;
                float vo = __shfl_xor(val, 1);
                uint_t packed = (lm & 1)
                    ? ((uint_t)f2bf(vo)  | ((uint_t)f2bf(val) << 16))
                    : ((uint_t)f2bf(val) | ((uint_t)f2bf(vo)  << 16));
                if ((lm & 1) == 0)
                    *(uint_t*)&Cs[(row_l + r) * 72 + (gn_l & ~1)] = packed;
            }
        }
        ps += __shfl_xor(ps, 16); pq += __shfl_xor(pq, 16);
        ps += __shfl_xor(ps, 32); pq += __shfl_xor(pq, 32);
        if (lane < 16) {
            atomicAdd(&ssum[gn], ps);
            atomicAdd(&ssq[gn], pq);
        }
    }
    __syncthreads();
    const int srow = t >> 3;
    const int scol = (t & 7) * 8;
#pragma unroll
    for (int rep = 0; rep < 4; ++rep) {
        const int row = srow + rep * 32;
        uint4 v = *(const uint4*)&Cs[row * 72 + scol];
        *(uint4*)(C + (size_t)(m0 + row) * H_ + n0 + scol) = v;
    }
}

// ------------------------------- BN2 + ReLU + transpose (unchanged)
__global__ __launch_bounds__(256) void bn_out_kernel(
    const ushort_t* __restrict__ y, const float* __restrict__ ssum, const float* __restrict__ ssq,
    const float* __restrict__ g, const float* __restrict__ beta, float* __restrict__ out)
{
    __shared__ float tile[64][65];
    __shared__ float sc[64], sh[64];
    const float invN = 1.0f / (float)ROWS_;
    const int bid = blockIdx.x;
    const int b  = bid >> 8;
    const int nt = (bid >> 2) & 63;
    const int ot = bid & 3;
    const int t = threadIdx.x;
    if (t < 64) {
        int c = ot * 64 + t;
        float mu  = ssum[c] * invN;
        float var = ssq[c] * invN - mu * mu;
        float s   = rsqrtf(var + 1e-3f) * g[c];
        sc[t] = s;
        sh[t] = beta[c] - mu * s;
    }
    __syncthreads();
    const int n0 = nt * 64, o0 = ot * 64;
    const ushort_t* yb = y + ((size_t)b * N2_ + n0) * H_ + o0;
#pragma unroll
    for (int j = 0; j < 8; ++j) {
        int lin = j * 256 + t;
        int nl = lin >> 5, cu = (lin & 31) * 2;
        uint_t u = *(const uint_t*)&yb[(size_t)nl * H_ + cu];
        tile[nl][cu]     = fmaxf(bf2f((ushort_t)(u & 0xffff)) * sc[cu]     + sh[cu],     0.0f);
        tile[nl][cu + 1] = fmaxf(bf2f((ushort_t)(u >> 16))    * sc[cu + 1] + sh[cu + 1], 0.0f);
    }
    __syncthreads();
    float* ob = out + ((size_t)b * H_ + o0) * N2_ + n0;
#pragma unroll
    for (int j = 0; j < 16; ++j) {
        int lin = j * 256 + t;
        int ol = lin >> 6, nl = lin & 63;
        ob[(size_t)ol * N2_ + nl] = tile[nl][ol];
    }
}

// ----------------------------------------------------------------------------
extern "C" void kernel_launch(void* const* d_in, const int* in_sizes, int n_in,
                              void* d_out, int out_size, void* d_ws, size_t ws_size,
                              hipStream_t stream)
{
    (void)in_sizes; (void)n_in; (void)out_size; (void)ws_size;
    const float* points1   = (const float*)d_in[0];
    const float* points2   = (const float*)d_in[1];
    const float* features1 = (const float*)d_in[2];
    const float* features2 = (const float*)d_in[3];
    const float* skipf     = (const float*)d_in[4];
    const float* W1  = (const float*)d_in[5];
    const float* b1  = (const float*)d_in[6];
    const float* g1  = (const float*)d_in[7];
    const float* be1 = (const float*)d_in[8];
    const float* W2  = (const float*)d_in[9];
    const float* b2  = (const float*)d_in[10];
    const float* g2  = (const float*)d_in[11];
    const float* be2 = (const float*)d_in[12];
    float* out = (float*)d_out;

    char* ws = (char*)d_ws;
    float*    s1  = (float*)(ws + 0);
    float*    q1  = (float*)(ws + 1024);
    float*    s2  = (float*)(ws + 2048);
    float*    q2  = (float*)(ws + 3072);
    int*      ind = (int*)(ws + 4096);                 // 393216 B
    float*    wgt = (float*)(ws + 397312);             // 393216 B
    ushort_t* x   = (ushort_t*)(ws + 790528);          // 29,360,128 B (bf16 32768x448)
    ushort_t* y1b = (ushort_t*)(ws + 30150656);        // 16,777,216 B (bf16 raw y1)
    ushort_t* W1b = (ushort_t*)(ws + 63705088);        // 229,376 B
    ushort_t* W2b = (ushort_t*)(ws + 63934464);        // 131,072 B
    ushort_t* f1t = (ushort_t*)(ws + 64065536);        // 4,194,304 B (bf16 8x1024x256)
    ushort_t* y2b = x;                                 // alias: x dead after gemm1

    hipMemsetAsync(ws, 0, 4096, stream);               // zero BN stats

    fused_pre<<<dim3(3520), dim3(256), 0, stream>>>(points1, points2, ind, wgt,
                                                    features1, features2, skipf,
                                                    W1, W2, f1t, x, W1b, W2b);
    gather_x<<<dim3(4096), dim3(256), 0, stream>>>(f1t, ind, wgt, x);

    gemm1_glds<<<dim3(ROWS_ / 128 * 4), dim3(256), 0, stream>>>(x, W1b, b1, y1b, s1, q1);
    gemm2_fused<<<dim3(ROWS_ / 128 * 4), dim3(256), 0, stream>>>(y1b, W2b, b2, s1, q1, g1, be1, y2b, s2, q2);
    bn_out_kernel<<<dim3(2048), dim3(256), 0, stream>>>(y2b, s2, q2, g2, be2, out);
}

// Round 12
// 198.790 us; speedup vs baseline: 1.5549x; 1.0314x over previous
//
#include <hip/hip_runtime.h>
#include <cstdint>
#include <cstddef>

#define B_    8
#define N1_   1024
#define N2_   4096
#define C1_   256
#define C2_   128
#define CS_   64
#define CT_   448
#define H_    256
#define ROWS_ (B_ * N2_)   // 32768

typedef __attribute__((ext_vector_type(8))) short bf16x8;
typedef __attribute__((ext_vector_type(4))) float f32x4;
typedef unsigned short ushort_t;
typedef unsigned int   uint_t;

__device__ __forceinline__ ushort_t f2bf(float f) {
    uint_t u = __float_as_uint(f);
    u = (u + 0x7fffu + ((u >> 16) & 1u)) >> 16;   // RNE
    return (ushort_t)u;
}
__device__ __forceinline__ float bf2f(ushort_t h) {
    return __uint_as_float(((uint_t)h) << 16);
}
// async global->LDS, 16B per lane; LDS dst = wave-uniform base + lane*16
__device__ __forceinline__ void glds16(const void* g, void* l) {
    __builtin_amdgcn_global_load_lds(
        (const __attribute__((address_space(1))) void*)g,
        (__attribute__((address_space(3))) void*)l, 16, 0, 0);
}

// ---------------------------------------------------------------- fused KNN + prep
// (unchanged — proven)
__global__ __launch_bounds__(256) void fused_pre(
    const float* __restrict__ p1, const float* __restrict__ p2,
    int* __restrict__ ind, float* __restrict__ wout,
    const float* __restrict__ f1, const float* __restrict__ f2,
    const float* __restrict__ fs, const float* __restrict__ W1,
    const float* __restrict__ W2, ushort_t* __restrict__ f1t,
    ushort_t* __restrict__ x, ushort_t* __restrict__ W1b, ushort_t* __restrict__ W2b)
{
#pragma clang fp contract(off)
    __shared__ __align__(16) char smem[32000];
    const int t = threadIdx.x;
    const int bid = blockIdx.x;
    if (bid < 1024) {
        float4*   cand  = (float4*)(smem);
        float*    pvals = (float*)(smem + 16512);
        float*    thr   = (float*)(smem + 19584);
        ushort_t* lists = (ushort_t*)(smem + 19712);
        float*    pdd   = (float*)(smem + 25856);
        int*      pdi   = (int*)(smem + 28928);
        const int b  = bid >> 7;
        const int qb = (bid & 127) * 32;
        const float* pb1 = p1 + (size_t)b * 3 * N1_;
        for (int i = t; i < N1_; i += 256) {
            float X = pb1[i], Y = pb1[N1_ + i], Z = pb1[2 * N1_ + i];
            cand[i] = make_float4(X, Y, Z, (X * X + Y * Y) + Z * Z);
        }
        const int q = t & 31, split = t >> 5;
        const int n = qb + q;
        const float* pb2 = p2 + (size_t)b * 3 * N2_;
        const float ax = pb2[n], ay = pb2[N2_ + n], az = pb2[2 * N2_ + n];
        const float s2a = (ax * ax + ay * ay) + az * az;
        const float m2x = -2.0f * ax, m2y = -2.0f * ay, m2z = -2.0f * az;
        __syncthreads();
        const int ibeg = split * 128, iend = ibeg + 128;
        {
            float a0 = 3e38f, a1 = 3e38f, a2 = 3e38f;
            for (int i = ibeg; i < iend; ++i) {
                float4 c = cand[i];
                float fd = fmaf(c.x, m2x, fmaf(c.y, m2y, fmaf(c.z, m2z, s2a + c.w)));
                float o0 = a0, o1 = a1;
                a0 = fminf(o0, fd);
                a1 = __builtin_amdgcn_fmed3f(fd, o0, o1);
                a2 = __builtin_amdgcn_fmed3f(fd, o1, a2);
            }
            pvals[t * 3 + 0] = a0; pvals[t * 3 + 1] = a1; pvals[t * 3 + 2] = a2;
        }
        __syncthreads();
        if (t < 32) {
            float m0 = 3e38f, m1 = 3e38f, m2v = 3e38f;
#pragma unroll
            for (int g = 0; g < 8; ++g)
#pragma unroll
                for (int r = 0; r < 3; ++r) {
                    float v = pvals[(g * 32 + t) * 3 + r];
                    float o0 = m0, o1 = m1;
                    m0 = fminf(o0, v);
                    m1 = __builtin_amdgcn_fmed3f(v, o0, o1);
                    m2v = __builtin_amdgcn_fmed3f(v, o1, m2v);
                }
            thr[t] = m2v + 2e-3f;
        }
        __syncthreads();
        const float th = thr[q];
        ushort_t* mylist = lists + (q * 8 + split) * 12;
        int cnt = 0;
        for (int i = ibeg; i < iend; ++i) {
            float4 c = cand[i];
            float fd = fmaf(c.x, m2x, fmaf(c.y, m2y, fmaf(c.z, m2z, s2a + c.w)));
            if (fd <= th && cnt < 12) { mylist[cnt] = (ushort_t)i; cnt++; }
        }
        float e0 = 3e38f, e1 = 3e38f, e2 = 3e38f;
        int   j0 = 0, j1 = 0, j2 = 0;
        for (int k = 0; k < cnt; ++k) {
            const int i = mylist[k];
            float4 c = cand[i];
            float dot = (ax * c.x + ay * c.y) + az * c.z;
            float dd  = (s2a + c.w) - 2.0f * dot;
            float d   = sqrtf(fmaxf(dd, 0.0f));
            if (d < e0)      { e2 = e1; j2 = j1; e1 = e0; j1 = j0; e0 = d; j0 = i; }
            else if (d < e1) { e2 = e1; j2 = j1; e1 = d;  j1 = i; }
            else if (d < e2) { e2 = d;  j2 = i; }
        }
        pdd[(split * 32 + q) * 3 + 0] = e0; pdi[(split * 32 + q) * 3 + 0] = j0;
        pdd[(split * 32 + q) * 3 + 1] = e1; pdi[(split * 32 + q) * 3 + 1] = j1;
        pdd[(split * 32 + q) * 3 + 2] = e2; pdi[(split * 32 + q) * 3 + 2] = j2;
        __syncthreads();
        if (t < 32) {
            float f0 = 3e38f, f1v = 3e38f, f2v = 3e38f;
            int   k0 = 0, k1 = 0, k2 = 0;
#pragma unroll
            for (int g = 0; g < 8; ++g)
#pragma unroll
                for (int r = 0; r < 3; ++r) {
                    float d = pdd[(g * 32 + t) * 3 + r];
                    int   i = pdi[(g * 32 + t) * 3 + r];
                    if (d < f0)       { f2v = f1v; k2 = k1; f1v = f0; k1 = k0; f0 = d; k0 = i; }
                    else if (d < f1v) { f2v = f1v; k2 = k1; f1v = d;  k1 = i; }
                    else if (d < f2v) { f2v = d;  k2 = i; }
                }
            float inv0 = 1.0f / (f0 + 1e-10f);
            float inv1 = 1.0f / (f1v + 1e-10f);
            float inv2 = 1.0f / (f2v + 1e-10f);
            float s = (inv0 + inv1) + inv2;
            const size_t row = (size_t)b * N2_ + qb + t;
            wout[row * 3 + 0] = inv0 / s;
            wout[row * 3 + 1] = inv1 / s;
            wout[row * 3 + 2] = inv2 / s;
            ind[row * 3 + 0] = k0;
            ind[row * 3 + 1] = k1;
            ind[row * 3 + 2] = k2;
        }
    } else if (bid < 1536) {
        float (*tile)[65] = (float (*)[65])smem;
        const int bid2 = bid - 1024;
        const int b  = bid2 >> 6;
        const int ct = (bid2 >> 4) & 3;
        const int nt = bid2 & 15;
        const int c0 = ct * 64, n0 = nt * 64;
        const float* src = f1 + ((size_t)b * C1_ + c0) * N1_ + n0;
#pragma unroll
        for (int j = 0; j < 16; ++j) {
            int lin = j * 256 + t;
            int ci = lin >> 6, nj = lin & 63;
            tile[ci][nj] = src[(size_t)ci * N1_ + nj];
        }
        __syncthreads();
        ushort_t* dst = f1t + ((size_t)b * N1_ + n0) * C1_ + c0;
#pragma unroll
        for (int j = 0; j < 8; ++j) {
            int lin = j * 256 + t;
            int ni = lin >> 5, cjp = (lin & 31) * 2;
            uint_t u = (uint_t)f2bf(tile[cjp][ni]) | ((uint_t)f2bf(tile[cjp + 1][ni]) << 16);
            *(uint_t*)&dst[(size_t)ni * C1_ + cjp] = u;
        }
    } else if (bid < 3072) {
        float (*tile)[65] = (float (*)[65])smem;
        const int bid2 = bid - 1536;
        const int b   = bid2 / 192;
        const int rem = bid2 - b * 192;
        const int ct  = rem >> 6;
        const int nt  = rem & 63;
        const float* src;
        int coff;
        if (ct < 2) { src = f2 + ((size_t)b * C2_ + ct * 64) * N2_; coff = C1_ + ct * 64; }
        else        { src = fs + (size_t)b * CS_ * N2_;             coff = C1_ + C2_; }
        const int n0 = nt * 64;
#pragma unroll
        for (int j = 0; j < 16; ++j) {
            int lin = j * 256 + t;
            int ci = lin >> 6, nj = lin & 63;
            tile[ci][nj] = src[(size_t)ci * N2_ + n0 + nj];
        }
        __syncthreads();
#pragma unroll
        for (int j = 0; j < 8; ++j) {
            int lin = j * 256 + t;
            int ni = lin >> 5, cjp = (lin & 31) * 2;
            uint_t u = (uint_t)f2bf(tile[cjp][ni]) | ((uint_t)f2bf(tile[cjp + 1][ni]) << 16);
            *(uint_t*)&x[((size_t)b * N2_ + n0 + ni) * CT_ + coff + cjp] = u;
        }
    } else {
        const int i = (bid - 3072) * 256 + t;
        if (i < H_ * CT_) W1b[i] = f2bf(W1[i]);
        if (i < H_ * H_)  W2b[i] = f2bf(W2[i]);
    }
}

// ------------------------------- gather+interp -> x_bf16[:, 0:256] (unchanged)
__global__ __launch_bounds__(256) void gather_x(
    const ushort_t* __restrict__ f1t, const int* __restrict__ ind,
    const float* __restrict__ w, ushort_t* __restrict__ x)
{
    const int t = threadIdx.x;
    const int row = blockIdx.x * 8 + (t >> 5);
    const int b = row >> 12;
    const int cg = (t & 31) * 8;
    const int*   ip = ind + (size_t)row * 3;
    const float* wp = w   + (size_t)row * 3;
    const int i0 = ip[0], i1 = ip[1], i2 = ip[2];
    const float w0 = wp[0], w1 = wp[1], w2 = wp[2];
    const ushort_t* base = f1t + (size_t)b * N1_ * C1_;
    uint4 va = *(const uint4*)(base + (size_t)i0 * C1_ + cg);
    uint4 vb = *(const uint4*)(base + (size_t)i1 * C1_ + cg);
    uint4 vc = *(const uint4*)(base + (size_t)i2 * C1_ + cg);
    const uint_t* pa = (const uint_t*)&va;
    const uint_t* pb = (const uint_t*)&vb;
    const uint_t* pc = (const uint_t*)&vc;
    uint_t out[4];
#pragma unroll
    for (int e = 0; e < 4; ++e) {
        float lo = w0 * bf2f((ushort_t)(pa[e] & 0xffff))
                 + w1 * bf2f((ushort_t)(pb[e] & 0xffff))
                 + w2 * bf2f((ushort_t)(pc[e] & 0xffff));
        float hi = w0 * bf2f((ushort_t)(pa[e] >> 16))
                 + w1 * bf2f((ushort_t)(pb[e] >> 16))
                 + w2 * bf2f((ushort_t)(pc[e] >> 16));
        out[e] = (uint_t)f2bf(lo) | ((uint_t)f2bf(hi) << 16);
    }
    *(uint4*)&x[(size_t)row * CT_ + cg] = *(uint4*)out;
}

// ------------------------------- GEMM1: BK=64, all-glds, XOR-swizzled 128B-row LDS.
// slot(row, c) = c ^ (row&7); glds lane pattern (lane&7)^(lane>>3) permutes within
// one 128B line (coalesced); b128 reads hit each bank-quad 2x (free). 7 barrier-
// pairs for K=448 (vs 14 at BK=32). Epilogue: R8-proven Cs full-line stores.
__global__ __launch_bounds__(256, 4) void gemm1_glds(
    const ushort_t* __restrict__ A, const ushort_t* __restrict__ Bw,
    const float* __restrict__ bias, ushort_t* __restrict__ C,
    float* __restrict__ ssum, float* __restrict__ ssq)
{
    __shared__ __align__(16) ushort_t smem[12288];   // A 128x64 + B 64x64 = 24KB
    ushort_t* As = smem;            // 128 rows x 64 (128B rows, swizzled)
    ushort_t* Bs = smem + 8192;     //  64 rows x 64
    ushort_t* Cs = smem;            // epilogue reuse (128x72 = 9216 shorts)
    const int t = threadIdx.x;
    const int m0 = (blockIdx.x >> 2) * 128;
    const int n0 = (blockIdx.x & 3) * 64;
    const int lane = t & 63;
    const int wv = t >> 6;
    const int wrow = wv & 1, wcol = wv >> 1;
    const int lm = lane & 15, lq = lane >> 4;
    const int lrow8  = lane >> 3;                      // 0..7
    const int lchunk = (lane & 7) ^ lrow8;             // swizzled source chunk
    const ushort_t* gA = A  + (size_t)(m0 + wv * 32 + lrow8) * CT_ + lchunk * 8;
    const ushort_t* gB = Bw + (size_t)(n0 + wv * 16 + lrow8) * CT_ + lchunk * 8;
    ushort_t* lA = As + wv * 2048;
    ushort_t* lB = Bs + wv * 1024;
    const int aswz = lm & 7;                           // read-side row swizzle
    f32x4 acc[4][2];
#pragma unroll
    for (int i = 0; i < 4; ++i)
#pragma unroll
        for (int j = 0; j < 2; ++j)
            acc[i][j] = (f32x4){0.f, 0.f, 0.f, 0.f};

    for (int k0 = 0; k0 < CT_; k0 += 64) {
        __syncthreads();                  // previous iter's LDS reads complete
#pragma unroll
        for (int g = 0; g < 4; ++g)
            glds16(gA + k0 + g * 8 * CT_, lA + g * 512);
#pragma unroll
        for (int g = 0; g < 2; ++g)
            glds16(gB + k0 + g * 8 * CT_, lB + g * 512);
        __syncthreads();                  // drains vmcnt -> tiles in LDS
#pragma unroll
        for (int h = 0; h < 2; ++h) {
            bf16x8 af[4], bfr[2];
#pragma unroll
            for (int i = 0; i < 4; ++i)
                af[i] = *(const bf16x8*)&As[(wrow * 64 + i * 16 + lm) * 64
                                            + (((h * 4 + lq) ^ aswz)) * 8];
#pragma unroll
            for (int j = 0; j < 2; ++j)
                bfr[j] = *(const bf16x8*)&Bs[(wcol * 32 + j * 16 + lm) * 64
                                             + (((h * 4 + lq) ^ aswz)) * 8];
#pragma unroll
            for (int i = 0; i < 4; ++i)
#pragma unroll
                for (int j = 0; j < 2; ++j)
                    acc[i][j] = __builtin_amdgcn_mfma_f32_16x16x32_bf16(af[i], bfr[j], acc[i][j], 0, 0, 0);
        }
    }
    __syncthreads();
#pragma unroll
    for (int j = 0; j < 2; ++j) {
        const int gn_l = wcol * 32 + j * 16 + lm;
        const int gn   = n0 + gn_l;
        const float bb = bias[gn];
        float ps = 0.0f, pq = 0.0f;
#pragma unroll
        for (int i = 0; i < 4; ++i) {
            const int row_l = wrow * 64 + i * 16 + lq * 4;
            f32x4 v = acc[i][j];
#pragma unroll
            for (int r = 0; r < 4; ++r) {
                float val = v[r] + bb;
                ps += val;
                pq += val * val;
                float vo = __shfl_xor(val, 1);
                uint_t packed = (lm & 1)
                    ? ((uint_t)f2bf(vo)  | ((uint_t)f2bf(val) << 16))
                    : ((uint_t)f2bf(val) | ((uint_t)f2bf(vo)  << 16));
                if ((lm & 1) == 0)
                    *(uint_t*)&Cs[(row_l + r) * 72 + (gn_l & ~1)] = packed;
            }
        }
        ps += __shfl_xor(ps, 16); pq += __shfl_xor(pq, 16);
        ps += __shfl_xor(ps, 32); pq += __shfl_xor(pq, 32);
        if (lane < 16) {
            atomicAdd(&ssum[gn], ps);
            atomicAdd(&ssq[gn], pq);
        }
    }
    __syncthreads();
    const int srow = t >> 3;
    const int scol = (t & 7) * 8;
#pragma unroll
    for (int rep = 0; rep < 4; ++rep) {
        const int row = srow + rep * 32;
        uint4 v = *(const uint4*)&Cs[row * 72 + scol];
        *(uint4*)(C + (size_t)(m0 + row) * H_ + n0 + scol) = v;
    }
}

// ------------------------------- GEMM2: BK=64, BN1+ReLU fused A-staging into two
// padded-40 half-arrays (bit-identical math + accumulation order vs BK=32 pair),
// B via glds+swizzle. 4 barrier-pairs for K=256 (vs 8).
__global__ __launch_bounds__(256, 4) void gemm2_fused(
    const ushort_t* __restrict__ A, const ushort_t* __restrict__ Bw,
    const float* __restrict__ bias,
    const float* __restrict__ s1, const float* __restrict__ q1,
    const float* __restrict__ g1, const float* __restrict__ be1,
    ushort_t* __restrict__ C, float* __restrict__ ssum, float* __restrict__ ssq)
{
    __shared__ __align__(16) ushort_t smem[15360];   // 30.7 KB
    ushort_t* As0 = smem;                    // 128 x 40 padded (k-half 0)
    ushort_t* As1 = smem + 5120;             // 128 x 40 padded (k-half 1)
    ushort_t* Bs  = smem + 10240;            //  64 x 64 swizzled (glds)
    float*    sc  = (float*)(smem + 14336);  // 256 floats
    float*    sh  = (float*)(smem + 14848);  // 256 floats
    ushort_t* Cs  = smem;                    // epilogue reuse
    const int t = threadIdx.x;
    const int m0 = (blockIdx.x >> 2) * 128;
    const int n0 = (blockIdx.x & 3) * 64;
    const int lane = t & 63;
    const int wv = t >> 6;
    const int wrow = wv & 1, wcol = wv >> 1;
    const int lm = lane & 15, lq = lane >> 4;
    const int lrow8  = lane >> 3;
    const int lchunk = (lane & 7) ^ lrow8;
    const int aswz = lm & 7;
    const int arow = t >> 1, acol = (t & 1) * 32;     // A staging: 32 cols/thread
    {
        const float invN = 1.0f / (float)ROWS_;
        float mu  = s1[t] * invN;
        float var = q1[t] * invN - mu * mu;
        float s   = rsqrtf(var + 1e-3f) * g1[t];
        sc[t] = s;
        sh[t] = be1[t] - mu * s;
    }
    const ushort_t* gB = Bw + (size_t)(n0 + wv * 16 + lrow8) * H_ + lchunk * 8;
    ushort_t* lB = Bs + wv * 1024;
    const ushort_t* gA = A + (size_t)(m0 + arow) * H_ + acol;
    ushort_t* As_t = (t & 1) ? As1 : As0;
    f32x4 acc[4][2];
#pragma unroll
    for (int i = 0; i < 4; ++i)
#pragma unroll
        for (int j = 0; j < 2; ++j)
            acc[i][j] = (f32x4){0.f, 0.f, 0.f, 0.f};

    for (int k0 = 0; k0 < H_; k0 += 64) {
        uint4 av[4];
#pragma unroll
        for (int g = 0; g < 4; ++g)
            av[g] = *(const uint4*)(gA + k0 + g * 8);   // issued before barrier
        __syncthreads();                  // prev reads done; sc/sh visible (1st iter)
#pragma unroll
        for (int g = 0; g < 2; ++g)
            glds16(gB + k0 + g * 8 * H_, lB + g * 512);
#pragma unroll
        for (int g = 0; g < 4; ++g) {
            const uint_t* wsrc = (const uint_t*)&av[g];
            uint_t o[4];
#pragma unroll
            for (int e = 0; e < 4; ++e) {
                const int cb = k0 + acol + g * 8 + 2 * e;
                float lo = __uint_as_float(wsrc[e] << 16);
                float hi = __uint_as_float(wsrc[e] & 0xffff0000u);
                float r0 = fmaxf(fmaf(lo, sc[cb],     sh[cb]),     0.0f);
                float r1 = fmaxf(fmaf(hi, sc[cb + 1], sh[cb + 1]), 0.0f);
                o[e] = (uint_t)f2bf(r0) | ((uint_t)f2bf(r1) << 16);
            }
            *(uint4*)&As_t[arow * 40 + g * 8] = *(uint4*)o;
        }
        __syncthreads();                  // drains vmcnt (B) + lgkm (As)
#pragma unroll
        for (int h = 0; h < 2; ++h) {
            const ushort_t* Ah = h ? As1 : As0;
            bf16x8 af[4], bfr[2];
#pragma unroll
            for (int i = 0; i < 4; ++i)
                af[i] = *(const bf16x8*)&Ah[(wrow * 64 + i * 16 + lm) * 40 + lq * 8];
#pragma unroll
            for (int j = 0; j < 2; ++j)
                bfr[j] = *(const bf16x8*)&Bs[(wcol * 32 + j * 16 + lm) * 64
                                             + (((h * 4 + lq) ^ aswz)) * 8];
#pragma unroll
            for (int i = 0; i < 4; ++i)
#pragma unroll
                for (int j = 0; j < 2; ++j)
                    acc[i][j] = __builtin_amdgcn_mfma_f32_16x16x32_bf16(af[i], bfr[j], acc[i][j], 0, 0, 0);
        }
    }
    __syncthreads();
#pragma unroll
    for (int j = 0; j < 2; ++j) {
        const int gn_l = wcol * 32 + j * 16 + lm;
        const int gn   = n0 + gn_l;
        const float bb = bias[gn];
        float ps = 0.0f, pq = 0.0f;
#pragma unroll
        for (int i = 0; i < 4; ++i) {
            const int row_l = wrow * 64 + i * 16 + lq * 4;
            f32x4 v = acc[i][j];
#pragma unroll
            for (int r = 0; r < 4; ++r) {
                float val = v[r] + bb;
                ps += val;
                pq += val * val;
                float vo = __shfl_xor(val, 1);
                uint_t packed = (lm & 1)
                    ? ((uint_t)f2bf(vo)  | ((uint_t)f2bf(val) << 16))
                    : ((uint_t)f2bf(val) | ((uint_t)f2bf(vo)  << 16));
                if ((lm & 1) == 0)
                    *(uint_t*)&Cs[(row_l + r) * 72 + (gn_l & ~1)] = packed;
            }
        }
        ps += __shfl_xor(ps, 16); pq += __shfl_xor(pq, 16);
        ps += __shfl_xor(ps, 32); pq += __shfl_xor(pq, 32);
        if (lane < 16) {
            atomicAdd(&ssum[gn], ps);
            atomicAdd(&ssq[gn], pq);
        }
    }
    __syncthreads();
    const int srow = t >> 3;
    const int scol = (t & 7) * 8;
#pragma unroll
    for (int rep = 0; rep < 4; ++rep) {
        const int row = srow + rep * 32;
        uint4 v = *(const uint4*)&Cs[row * 72 + scol];
        *(uint4*)(C + (size_t)(m0 + row) * H_ + n0 + scol) = v;
    }
}

// ------------------------------- BN2 + ReLU + transpose (unchanged)
__global__ __launch_bounds__(256) void bn_out_kernel(
    const ushort_t* __restrict__ y, const float* __restrict__ ssum, const float* __restrict__ ssq,
    const float* __restrict__ g, const float* __restrict__ beta, float* __restrict__ out)
{
    __shared__ float tile[64][65];
    __shared__ float sc[64], sh[64];
    const float invN = 1.0f / (float)ROWS_;
    const int bid = blockIdx.x;
    const int b  = bid >> 8;
    const int nt = (bid >> 2) & 63;
    const int ot = bid & 3;
    const int t = threadIdx.x;
    if (t < 64) {
        int c = ot * 64 + t;
        float mu  = ssum[c] * invN;
        float var = ssq[c] * invN - mu * mu;
        float s   = rsqrtf(var + 1e-3f) * g[c];
        sc[t] = s;
        sh[t] = beta[c] - mu * s;
    }
    __syncthreads();
    const int n0 = nt * 64, o0 = ot * 64;
    const ushort_t* yb = y + ((size_t)b * N2_ + n0) * H_ + o0;
#pragma unroll
    for (int j = 0; j < 8; ++j) {
        int lin = j * 256 + t;
        int nl = lin >> 5, cu = (lin & 31) * 2;
        uint_t u = *(const uint_t*)&yb[(size_t)nl * H_ + cu];
        tile[nl][cu]     = fmaxf(bf2f((ushort_t)(u & 0xffff)) * sc[cu]     + sh[cu],     0.0f);
        tile[nl][cu + 1] = fmaxf(bf2f((ushort_t)(u >> 16))    * sc[cu + 1] + sh[cu + 1], 0.0f);
    }
    __syncthreads();
    float* ob = out + ((size_t)b * H_ + o0) * N2_ + n0;
#pragma unroll
    for (int j = 0; j < 16; ++j) {
        int lin = j * 256 + t;
        int ol = lin >> 6, nl = lin & 63;
        ob[(size_t)ol * N2_ + nl] = tile[nl][ol];
    }
}

// ----------------------------------------------------------------------------
extern "C" void kernel_launch(void* const* d_in, const int* in_sizes, int n_in,
                              void* d_out, int out_size, void* d_ws, size_t ws_size,
                              hipStream_t stream)
{
    (void)in_sizes; (void)n_in; (void)out_size; (void)ws_size;
    const float* points1   = (const float*)d_in[0];
    const float* points2   = (const float*)d_in[1];
    const float* features1 = (const float*)d_in[2];
    const float* features2 = (const float*)d_in[3];
    const float* skipf     = (const float*)d_in[4];
    const float* W1  = (const float*)d_in[5];
    const float* b1  = (const float*)d_in[6];
    const float* g1  = (const float*)d_in[7];
    const float* be1 = (const float*)d_in[8];
    const float* W2  = (const float*)d_in[9];
    const float* b2  = (const float*)d_in[10];
    const float* g2  = (const float*)d_in[11];
    const float* be2 = (const float*)d_in[12];
    float* out = (float*)d_out;

    char* ws = (char*)d_ws;
    float*    s1  = (float*)(ws + 0);
    float*    q1  = (float*)(ws + 1024);
    float*    s2  = (float*)(ws + 2048);
    float*    q2  = (float*)(ws + 3072);
    int*      ind = (int*)(ws + 4096);                 // 393216 B
    float*    wgt = (float*)(ws + 397312);             // 393216 B
    ushort_t* x   = (ushort_t*)(ws + 790528);          // 29,360,128 B (bf16 32768x448)
    ushort_t* y1b = (ushort_t*)(ws + 30150656);        // 16,777,216 B (bf16 raw y1)
    ushort_t* W1b = (ushort_t*)(ws + 63705088);        // 229,376 B
    ushort_t* W2b = (ushort_t*)(ws + 63934464);        // 131,072 B
    ushort_t* f1t = (ushort_t*)(ws + 64065536);        // 4,194,304 B (bf16 8x1024x256)
    ushort_t* y2b = x;                                 // alias: x dead after gemm1

    hipMemsetAsync(ws, 0, 4096, stream);               // zero BN stats

    fused_pre<<<dim3(3520), dim3(256), 0, stream>>>(points1, points2, ind, wgt,
                                                    features1, features2, skipf,
                                                    W1, W2, f1t, x, W1b, W2b);
    gather_x<<<dim3(4096), dim3(256), 0, stream>>>(f1t, ind, wgt, x);

    gemm1_glds<<<dim3(ROWS_ / 128 * 4), dim3(256), 0, stream>>>(x, W1b, b1, y1b, s1, q1);
    gemm2_fused<<<dim3(ROWS_ / 128 * 4), dim3(256), 0, stream>>>(y1b, W2b, b2, s1, q1, g1, be1, y2b, s2, q2);
    bn_out_kernel<<<dim3(2048), dim3(256), 0, stream>>>(y2b, s2, q2, g2, be2, out);
}